// Round 2
// baseline (2171.308 us; speedup 1.0000x reference)
//
#include <hip/hip_runtime.h>
#include <stdint.h>

#define DD 256
#define DINF 128

typedef __attribute__((ext_vector_type(8))) short short8;
typedef __attribute__((ext_vector_type(4))) float f32x4;

__device__ __forceinline__ short f2bf(float f) {
    union { float f; uint32_t u; } c{f};
    uint32_t r = (c.u + 0x7fffu + ((c.u >> 16) & 1u)) >> 16;
    return (short)(uint16_t)r;
}

__device__ __forceinline__ float bf2f(uint16_t b) {
    union { uint32_t u; float f; } c;
    c.u = ((uint32_t)b) << 16;
    return c.f;
}

// ---------------- CSR build ----------------
__global__ void k_hist(const int* __restrict__ rows, int* __restrict__ counts, int E) {
    int e = blockIdx.x * blockDim.x + threadIdx.x;
    if (e < E) atomicAdd(&counts[rows[e] + 1], 1);
}

__global__ void k_scan1(const int* __restrict__ counts, int* __restrict__ part,
                        int* __restrict__ blksum, int n1) {
    __shared__ int tmp[1024];
    int b = blockIdx.x, t = threadIdx.x, i = b * 1024 + t;
    int v = (i < n1) ? counts[i] : 0;
    tmp[t] = v;
    __syncthreads();
    for (int off = 1; off < 1024; off <<= 1) {
        int a = (t >= off) ? tmp[t - off] : 0;
        __syncthreads();
        tmp[t] += a;
        __syncthreads();
    }
    if (i < n1) part[i] = tmp[t];
    if (t == 1023) blksum[b] = tmp[t];
}

__global__ void k_scan2(int* __restrict__ blksum, int nb) {
    __shared__ int tmp[1024];
    int t = threadIdx.x;
    int v = (t < nb) ? blksum[t] : 0;
    tmp[t] = v;
    __syncthreads();
    for (int off = 1; off < 1024; off <<= 1) {
        int a = (t >= off) ? tmp[t - off] : 0;
        __syncthreads();
        tmp[t] += a;
        __syncthreads();
    }
    if (t < nb) blksum[t] = tmp[t];
}

__global__ void k_scan3(const int* __restrict__ blksum, int* __restrict__ row_ptr,
                        int* __restrict__ cursor, int n1) {
    int i = blockIdx.x * blockDim.x + threadIdx.x;
    if (i < n1) {
        int b = i >> 10;
        int off = (b > 0) ? blksum[b - 1] : 0;
        int v = row_ptr[i] + off;
        row_ptr[i] = v;
        cursor[i] = v;
    }
}

__global__ void k_scatter(const int* __restrict__ rows, const int* __restrict__ cols,
                          const float* __restrict__ vals, int* __restrict__ cursor,
                          int* __restrict__ cols_s, float* __restrict__ vals_s, int E) {
    int e = blockIdx.x * blockDim.x + threadIdx.x;
    if (e < E) {
        int r = rows[e];
        int pos = atomicAdd(&cursor[r], 1);
        cols_s[pos] = cols[e];
        vals_s[pos] = vals[e];
    }
}

// ---------------- M = (W*clip(d))@W^T - I, packed in MFMA B-fragment order ----------------
__global__ void k_build_m(const float* __restrict__ W, const float* __restrict__ dvec,
                          uint16_t* __restrict__ Mpk) {
    __shared__ float u[DD];
    int n = blockIdx.x, k = threadIdx.x;
    float dj = dvec[k];
    dj = fminf(fmaxf(dj, 0.f), 1.f);
    u[k] = W[n * DD + k] * dj;
    __syncthreads();
    float acc = 0.f;
    for (int j = 0; j < DD; j++) acc += u[j] * W[k * DD + j];
    acc -= (n == k) ? 1.f : 0.f;
    int tile = n >> 4, m = n & 15, kt = k >> 5, quad = (k >> 3) & 3, j = k & 7;
    int lane = quad * 16 + m;
    Mpk[(((tile * 8 + kt) * 64 + lane) << 3) + j] = (uint16_t)f2bf(acc);
}

// ---------------- init: znb = bf16([x,0]), alpha = alpha0 ----------------
__global__ void k_init(const float* __restrict__ x, const float* __restrict__ alpha0,
                       uint16_t* __restrict__ znb, float* __restrict__ alpha, int N) {
    int idx = blockIdx.x * blockDim.x + threadIdx.x;
    int total = N * 64;
    if (idx < total) {
        int row = idx >> 6, c4 = idx & 63;
        float4 v = make_float4(0.f, 0.f, 0.f, 0.f);
        if (c4 < 32) v = ((const float4*)x)[(size_t)row * 32 + c4];
        ushort4 b;
        b.x = (uint16_t)f2bf(v.x); b.y = (uint16_t)f2bf(v.y);
        b.z = (uint16_t)f2bf(v.z); b.w = (uint16_t)f2bf(v.w);
        ((ushort4*)znb)[idx] = b;
    }
    if (idx < N) alpha[idx] = alpha0[idx];
}

// ---------------- SpMM + alpha: az = bf16(A*z); alpha update; alph = 0.5*sigmoid ------
__global__ void k_spmm(const uint16_t* __restrict__ z, const int* __restrict__ row_ptr,
                       const int* __restrict__ cols_s, const float* __restrict__ vals_s,
                       const float* __restrict__ W_ih, const float* __restrict__ W_hh,
                       const float* __restrict__ b_ih, const float* __restrict__ b_hh,
                       const float* __restrict__ hbuf, float* __restrict__ alpha,
                       float* __restrict__ alph, uint16_t* __restrict__ az, int N) {
    int wave = (int)((blockIdx.x * (size_t)blockDim.x + threadIdx.x) >> 6);
    int lane = threadIdx.x & 63;
    if (wave >= N) return;

    // own-row eval point (cols 4*lane..+3)
    ushort4 zr4 = ((const ushort4*)z)[(size_t)wave * 64 + lane];
    float z0 = bf2f(zr4.x), z1 = bf2f(zr4.y), z2 = bf2f(zr4.z), z3 = bf2f(zr4.w);

    // RNNCell dot partials
    float4 w0 = ((const float4*)W_ih)[lane];
    float4 w1 = ((const float4*)(W_ih + DD))[lane];
    float s0 = z0 * w0.x + z1 * w0.y + z2 * w0.z + z3 * w0.w;
    float s1 = z0 * w1.x + z1 * w1.y + z2 * w1.z + z3 * w1.w;

    // gather
    int s = row_ptr[wave], e = row_ptr[wave + 1];
    float4 acc = make_float4(0.f, 0.f, 0.f, 0.f);
    int c_next = 0; float v_next = 0.f;
    if (s < e) { c_next = cols_s[s]; v_next = vals_s[s]; }
    for (int i = s; i < e; i++) {
        int c = c_next; float v = v_next;
        if (i + 1 < e) { c_next = cols_s[i + 1]; v_next = vals_s[i + 1]; }
        ushort4 zr = ((const ushort4*)z)[(size_t)c * 64 + lane];
        acc.x += v * bf2f(zr.x); acc.y += v * bf2f(zr.y);
        acc.z += v * bf2f(zr.z); acc.w += v * bf2f(zr.w);
    }
    ushort4 o;
    o.x = (uint16_t)f2bf(acc.x); o.y = (uint16_t)f2bf(acc.y);
    o.z = (uint16_t)f2bf(acc.z); o.w = (uint16_t)f2bf(acc.w);
    ((ushort4*)az)[(size_t)wave * 64 + lane] = o;

    // wave-reduce the dots, lane 0 does the alpha update
    #pragma unroll
    for (int off = 32; off >= 1; off >>= 1) {
        s0 += __shfl_down(s0, off, 64);
        s1 += __shfl_down(s1, off, 64);
    }
    if (lane == 0) {
        float h0 = hbuf[wave * 2], h1 = hbuf[wave * 2 + 1];
        float cc0 = b_ih[0] + b_hh[0] + h0 * W_hh[0] + h1 * W_hh[1];
        float cc1 = b_ih[1] + b_hh[1] + h0 * W_hh[2] + h1 * W_hh[3];
        float anew = alpha[wave] * tanhf(s0 + cc0) + tanhf(s1 + cc1);
        alpha[wave] = anew;
        alph[wave] = 0.5f / (1.f + expf(-anew));
    }
}

// ---------------- eval: z@M (MFMA) + in-register combine + RK4 ----------------
// f = alph*(az - z) + z@M + x0   (z rows staged in LDS; MFMA frags consumed in place)
// mode 0: zout = bf16(z + c1*f)   ; S = z + c2*f
// mode 1: zout = bf16(znb + c1*f) ; S += c2*f
// mode 2: zout = bf16(S + c2*f)
// mode 3: out(f32, first 128 cols) = S + c2*f    (final eval; no zout write)
__global__ __launch_bounds__(256, 6) void k_eval(
    const uint16_t* __restrict__ zsrc, const uint16_t* __restrict__ znb,
    uint16_t* __restrict__ zout, float* __restrict__ S, float* __restrict__ out,
    const uint16_t* __restrict__ az, const uint16_t* __restrict__ Mpk,
    const float* __restrict__ x, const float* __restrict__ alph,
    int N, int mode, float c1, float c2)
{
    __shared__ uint16_t zs[32][264];   // eval-point rows, bf16  ~16.9 KB
    __shared__ float alph_s[32];

    int t = threadIdx.x;
    int r0 = blockIdx.x * 32;
    int wv = t >> 6;
    int lane = t & 63;

    // P0: stage own 32 bf16 rows + alph
    #pragma unroll
    for (int i = 0; i < 8; i++) {
        int idx = t + i * 256;
        int row = idx >> 6, c4 = idx & 63;
        int grow = r0 + row;
        ushort4 v = make_ushort4(0, 0, 0, 0);
        if (grow < N) v = ((const ushort4*)zsrc)[(size_t)grow * 64 + c4];
        *(ushort4*)&zs[row][c4 * 4] = v;
    }
    if (t < 32) alph_s[t] = (r0 + t < N) ? alph[r0 + t] : 0.f;
    __syncthreads();

    // P1: A fragments from LDS
    int m = lane & 15, quad = lane >> 4;
    int half = wv & 1, whichW = wv >> 1;
    int arow = half * 16 + m;
    int lrb = half * 16 + quad * 4;
    short8 afr[8];
    #pragma unroll
    for (int kt = 0; kt < 8; kt++)
        afr[kt] = *(const short8*)&zs[arow][kt * 32 + quad * 8];

    float alr[4];
    #pragma unroll
    for (int r = 0; r < 4; r++) alr[r] = alph_s[lrb + r];

    // P2: per column tile: MFMA chain then in-register combine at fragment positions.
    // Fragment (nt, r) lives at global (row r0+lrb+r, col tile*16+m).
    #pragma unroll
    for (int nt = 0; nt < 8; nt++) {
        int tile = whichW * 8 + nt;
        f32x4 acc = {0.f, 0.f, 0.f, 0.f};
        #pragma unroll
        for (int kt = 0; kt < 8; kt++) {
            short8 b = ((const short8*)Mpk)[(tile * 8 + kt) * 64 + lane];
            acc = __builtin_amdgcn_mfma_f32_16x16x32_bf16(afr[kt], b, acc, 0, 0, 0);
        }
        int gcol = tile * 16 + m;
        #pragma unroll
        for (int r = 0; r < 4; r++) {
            int grow = r0 + lrb + r;
            if (grow >= N) continue;
            size_t pos = (size_t)grow * 256 + gcol;
            float zv = bf2f(zs[lrb + r][gcol]);
            float av = bf2f(az[pos]);
            float xv = (whichW == 0) ? x[(size_t)grow * 128 + gcol] : 0.f;
            float f = alr[r] * (av - zv) + acc[r] + xv;
            if (mode == 0) {
                zout[pos] = (uint16_t)f2bf(zv + c1 * f);
                S[pos] = zv + c2 * f;
            } else if (mode == 1) {
                float zb = bf2f(znb[pos]);
                zout[pos] = (uint16_t)f2bf(zb + c1 * f);
                S[pos] += c2 * f;
            } else if (mode == 2) {
                zout[pos] = (uint16_t)f2bf(S[pos] + c2 * f);
            } else {
                if (whichW == 0) out[(size_t)grow * 128 + gcol] = S[pos] + c2 * f;
            }
        }
    }
}

__global__ void k_fill(float* __restrict__ out, int n, float v) {
    int idx = blockIdx.x * blockDim.x + threadIdx.x;
    if (idx < n) out[idx] = v;
}

static inline size_t alignup(size_t v) { return (v + 255) & ~(size_t)255; }

extern "C" void kernel_launch(void* const* d_in, const int* in_sizes, int n_in,
                              void* d_out, int out_size, void* d_ws, size_t ws_size,
                              hipStream_t stream) {
    const float* x      = (const float*)d_in[0];
    const int*   erow   = (const int*)d_in[1];
    const int*   ecol   = (const int*)d_in[2];
    const float* evals  = (const float*)d_in[3];
    const float* W_ih   = (const float*)d_in[4];
    const float* W_hh   = (const float*)d_in[5];
    const float* b_ih   = (const float*)d_in[6];
    const float* b_hh   = (const float*)d_in[7];
    const float* h      = (const float*)d_in[8];
    const float* alpha0 = (const float*)d_in[9];
    const float* W      = (const float*)d_in[10];
    const float* dvec   = (const float*)d_in[11];

    int N = in_sizes[0] / DINF;
    int E = in_sizes[1];

    char* w = (char*)d_ws;
    uint16_t* znb = (uint16_t*)w; w += alignup((size_t)N * DD * 2);   //  51.2 MB
    float* S  = (float*)w;        w += alignup((size_t)N * DD * 4);   // 102.4 MB
    uint16_t* zpA = (uint16_t*)w; w += alignup((size_t)N * DD * 2);   //  51.2 MB
    uint16_t* az = (uint16_t*)w;  w += alignup((size_t)N * DD * 2);   //  51.2 MB
    float* alpha = (float*)w;     w += alignup((size_t)N * 4);
    float* alph = (float*)w;      w += alignup((size_t)N * 4);
    uint16_t* Mpk = (uint16_t*)w; w += alignup((size_t)DD * DD * 2);
    int* counts = (int*)w;        w += alignup((size_t)(N + 1) * 4);  // reused as cursor
    int* row_ptr = (int*)w;       w += alignup((size_t)(N + 1) * 4);
    int* blksum = (int*)w;        w += alignup((size_t)1024 * 4);
    int* cols_s = (int*)w;        w += alignup((size_t)E * 4);
    float* vals_s = (float*)w;    w += alignup((size_t)E * 4);
    size_t need = (size_t)(w - (char*)d_ws);   // ~264 MB

    // zpB (bf16 ping-pong partner) lives in d_out; its last read (eval3 of step 2)
    // precedes the final mode-3 eval that overwrites d_out with the fp32 result.
    uint16_t* zpB = (uint16_t*)d_out;

    if (ws_size < need) {
        k_fill<<<(out_size + 255) / 256, 256, 0, stream>>>((float*)d_out, out_size, 1000.0f);
        return;
    }

    int n1 = N + 1, nb = (n1 + 1023) / 1024;
    hipMemsetAsync(counts, 0, (size_t)n1 * 4, stream);
    k_hist<<<(E + 255) / 256, 256, 0, stream>>>(erow, counts, E);
    k_scan1<<<nb, 1024, 0, stream>>>(counts, row_ptr, blksum, n1);
    k_scan2<<<1, 1024, 0, stream>>>(blksum, nb);
    k_scan3<<<(n1 + 255) / 256, 256, 0, stream>>>(blksum, row_ptr, counts, n1);
    k_scatter<<<(E + 255) / 256, 256, 0, stream>>>(erow, ecol, evals, counts, cols_s, vals_s, E);

    k_build_m<<<DD, DD, 0, stream>>>(W, dvec, Mpk);
    k_init<<<(N * 64 + 255) / 256, 256, 0, stream>>>(x, alpha0, znb, alpha, N);

    const float dt = 0.45f;  // T_END / N_STEPS
    int gs = (N + 3) / 4, ge = (N + 31) / 32;
    for (int s = 0; s < 2; s++) {
        // eval1: z = znb -> eval point zpA
        k_spmm<<<gs, 256, 0, stream>>>(znb, row_ptr, cols_s, vals_s, W_ih, W_hh,
                                       b_ih, b_hh, h, alpha, alph, az, N);
        k_eval<<<ge, 256, 0, stream>>>(znb, znb, zpA, S, nullptr, az, Mpk, x, alph,
                                       N, 0, 0.5f * dt, dt / 6.f);
        // eval2: z = zpA -> zpB
        k_spmm<<<gs, 256, 0, stream>>>(zpA, row_ptr, cols_s, vals_s, W_ih, W_hh,
                                       b_ih, b_hh, h, alpha, alph, az, N);
        k_eval<<<ge, 256, 0, stream>>>(zpA, znb, zpB, S, nullptr, az, Mpk, x, alph,
                                       N, 1, 0.5f * dt, dt / 3.f);
        // eval3: z = zpB -> zpA
        k_spmm<<<gs, 256, 0, stream>>>(zpB, row_ptr, cols_s, vals_s, W_ih, W_hh,
                                       b_ih, b_hh, h, alpha, alph, az, N);
        k_eval<<<ge, 256, 0, stream>>>(zpB, znb, zpA, S, nullptr, az, Mpk, x, alph,
                                       N, 1, dt, dt / 3.f);
        // eval4
        k_spmm<<<gs, 256, 0, stream>>>(zpA, row_ptr, cols_s, vals_s, W_ih, W_hh,
                                       b_ih, b_hh, h, alpha, alph, az, N);
        if (s == 0) {
            k_eval<<<ge, 256, 0, stream>>>(zpA, znb, znb, S, nullptr, az, Mpk, x, alph,
                                           N, 2, 0.f, dt / 6.f);
        } else {
            // final eval: emit fp32 output directly (first 128 cols)
            k_eval<<<ge, 256, 0, stream>>>(zpA, znb, znb, S, (float*)d_out, az, Mpk, x, alph,
                                           N, 3, 0.f, dt / 6.f);
        }
    }
}

// Round 3
// 1988.924 us; speedup vs baseline: 1.0917x; 1.0917x over previous
//
#include <hip/hip_runtime.h>
#include <stdint.h>

#define DD 256
#define DINF 128

typedef __attribute__((ext_vector_type(8))) short short8;
typedef __attribute__((ext_vector_type(4))) float f32x4;

__device__ __forceinline__ short f2bf(float f) {
    union { float f; uint32_t u; } c{f};
    uint32_t r = (c.u + 0x7fffu + ((c.u >> 16) & 1u)) >> 16;
    return (short)(uint16_t)r;
}

__device__ __forceinline__ float bf2f(uint16_t b) {
    union { uint32_t u; float f; } c;
    c.u = ((uint32_t)b) << 16;
    return c.f;
}

// ---------------- CSR build ----------------
__global__ void k_hist(const int* __restrict__ rows, int* __restrict__ counts, int E) {
    int e = blockIdx.x * blockDim.x + threadIdx.x;
    if (e < E) atomicAdd(&counts[rows[e] + 1], 1);
}

__global__ void k_scan1(const int* __restrict__ counts, int* __restrict__ part,
                        int* __restrict__ blksum, int n1) {
    __shared__ int tmp[1024];
    int b = blockIdx.x, t = threadIdx.x, i = b * 1024 + t;
    int v = (i < n1) ? counts[i] : 0;
    tmp[t] = v;
    __syncthreads();
    for (int off = 1; off < 1024; off <<= 1) {
        int a = (t >= off) ? tmp[t - off] : 0;
        __syncthreads();
        tmp[t] += a;
        __syncthreads();
    }
    if (i < n1) part[i] = tmp[t];
    if (t == 1023) blksum[b] = tmp[t];
}

__global__ void k_scan2(int* __restrict__ blksum, int nb) {
    __shared__ int tmp[1024];
    int t = threadIdx.x;
    int v = (t < nb) ? blksum[t] : 0;
    tmp[t] = v;
    __syncthreads();
    for (int off = 1; off < 1024; off <<= 1) {
        int a = (t >= off) ? tmp[t - off] : 0;
        __syncthreads();
        tmp[t] += a;
        __syncthreads();
    }
    if (t < nb) blksum[t] = tmp[t];
}

__global__ void k_scan3(const int* __restrict__ blksum, int* __restrict__ row_ptr,
                        int* __restrict__ cursor, int n1) {
    int i = blockIdx.x * blockDim.x + threadIdx.x;
    if (i < n1) {
        int b = i >> 10;
        int off = (b > 0) ? blksum[b - 1] : 0;
        int v = row_ptr[i] + off;
        row_ptr[i] = v;
        cursor[i] = v;
    }
}

__global__ void k_scatter(const int* __restrict__ rows, const int* __restrict__ cols,
                          const float* __restrict__ vals, int* __restrict__ cursor,
                          int* __restrict__ cols_s, float* __restrict__ vals_s, int E) {
    int e = blockIdx.x * blockDim.x + threadIdx.x;
    if (e < E) {
        int r = rows[e];
        int pos = atomicAdd(&cursor[r], 1);
        cols_s[pos] = cols[e];
        vals_s[pos] = vals[e];
    }
}

// ---------------- M = (W*clip(d))@W^T - I, packed in MFMA B-fragment order ----------------
__global__ void k_build_m(const float* __restrict__ W, const float* __restrict__ dvec,
                          uint16_t* __restrict__ Mpk) {
    __shared__ float u[DD];
    int n = blockIdx.x, k = threadIdx.x;
    float dj = dvec[k];
    dj = fminf(fmaxf(dj, 0.f), 1.f);
    u[k] = W[n * DD + k] * dj;
    __syncthreads();
    float acc = 0.f;
    for (int j = 0; j < DD; j++) acc += u[j] * W[k * DD + j];
    acc -= (n == k) ? 1.f : 0.f;
    int tile = n >> 4, m = n & 15, kt = k >> 5, quad = (k >> 3) & 3, j = k & 7;
    int lane = quad * 16 + m;
    Mpk[(((tile * 8 + kt) * 64 + lane) << 3) + j] = (uint16_t)f2bf(acc);
}

// ---------------- init: znb = bf16([x,0]), alpha = alpha0 ----------------
__global__ void k_init(const float* __restrict__ x, const float* __restrict__ alpha0,
                       uint16_t* __restrict__ znb, float* __restrict__ alpha, int N) {
    int idx = blockIdx.x * blockDim.x + threadIdx.x;
    int total = N * 64;
    if (idx < total) {
        int row = idx >> 6, c4 = idx & 63;
        float4 v = make_float4(0.f, 0.f, 0.f, 0.f);
        if (c4 < 32) v = ((const float4*)x)[(size_t)row * 32 + c4];
        ushort4 b;
        b.x = (uint16_t)f2bf(v.x); b.y = (uint16_t)f2bf(v.y);
        b.z = (uint16_t)f2bf(v.z); b.w = (uint16_t)f2bf(v.w);
        ((ushort4*)znb)[idx] = b;
    }
    if (idx < N) alpha[idx] = alpha0[idx];
}

// ---------------- SpMM + alpha, 4 rows per wave ----------------
// az = bf16(A*z); alpha update; alph = 0.5*sigmoid(alpha)
#define RPW 4
__global__ void k_spmm(const uint16_t* __restrict__ z, const int* __restrict__ row_ptr,
                       const int* __restrict__ cols_s, const float* __restrict__ vals_s,
                       const float* __restrict__ W_ih, const float* __restrict__ W_hh,
                       const float* __restrict__ b_ih, const float* __restrict__ b_hh,
                       const float* __restrict__ hbuf, float* __restrict__ alpha,
                       float* __restrict__ alph, uint16_t* __restrict__ az, int N) {
    int wave = (int)((blockIdx.x * (size_t)blockDim.x + threadIdx.x) >> 6);
    int lane = threadIdx.x & 63;
    int r0 = wave * RPW;
    if (r0 >= N) return;

    float4 w0 = ((const float4*)W_ih)[lane];
    float4 w1 = ((const float4*)(W_ih + DD))[lane];

    int   rs[RPW], re[RPW];
    float s0[RPW], s1[RPW];
    float4 acc[RPW];
    int maxd = 0;
    #pragma unroll
    for (int r = 0; r < RPW; r++) {
        int row = r0 + r;
        bool ok = row < N;
        rs[r] = ok ? row_ptr[row] : 0;
        re[r] = ok ? row_ptr[row + 1] : 0;
        int d = re[r] - rs[r];
        maxd = (d > maxd) ? d : maxd;
        ushort4 zr4 = ok ? ((const ushort4*)z)[(size_t)row * 64 + lane]
                         : make_ushort4(0, 0, 0, 0);
        float z0 = bf2f(zr4.x), z1 = bf2f(zr4.y), z2 = bf2f(zr4.z), z3 = bf2f(zr4.w);
        s0[r] = z0 * w0.x + z1 * w0.y + z2 * w0.z + z3 * w0.w;
        s1[r] = z0 * w1.x + z1 * w1.y + z2 * w1.z + z3 * w1.w;
        acc[r] = make_float4(0.f, 0.f, 0.f, 0.f);
    }

    // interleaved gather: 4 independent load chains per iteration
    for (int i = 0; i < maxd; i++) {
        #pragma unroll
        for (int r = 0; r < RPW; r++) {
            int idx = rs[r] + i;
            if (idx < re[r]) {
                int c = cols_s[idx];
                float v = vals_s[idx];
                ushort4 zr = ((const ushort4*)z)[(size_t)c * 64 + lane];
                acc[r].x += v * bf2f(zr.x); acc[r].y += v * bf2f(zr.y);
                acc[r].z += v * bf2f(zr.z); acc[r].w += v * bf2f(zr.w);
            }
        }
    }

    #pragma unroll
    for (int r = 0; r < RPW; r++) {
        int row = r0 + r;
        if (row >= N) continue;
        ushort4 o;
        o.x = (uint16_t)f2bf(acc[r].x); o.y = (uint16_t)f2bf(acc[r].y);
        o.z = (uint16_t)f2bf(acc[r].z); o.w = (uint16_t)f2bf(acc[r].w);
        ((ushort4*)az)[(size_t)row * 64 + lane] = o;

        float t0 = s0[r], t1 = s1[r];
        #pragma unroll
        for (int off = 32; off >= 1; off >>= 1) {
            t0 += __shfl_down(t0, off, 64);
            t1 += __shfl_down(t1, off, 64);
        }
        if (lane == 0) {
            float h0 = hbuf[row * 2], h1 = hbuf[row * 2 + 1];
            float cc0 = b_ih[0] + b_hh[0] + h0 * W_hh[0] + h1 * W_hh[1];
            float cc1 = b_ih[1] + b_hh[1] + h0 * W_hh[2] + h1 * W_hh[3];
            float anew = alpha[row] * tanhf(t0 + cc0) + tanhf(t1 + cc1);
            alpha[row] = anew;
            alph[row] = 0.5f / (1.f + expf(-anew));
        }
    }
}

// ---------------- eval: z@M (MFMA) + combine + RK4 ----------------
// f = alph*(az - z) + z@M + x0
// A-fragments and P3 z-values read directly from global zsrc (L1/L2-hot 16KB slab);
// only the MFMA result gs lives in LDS -> 17 KB -> 8 blocks/CU.
// mode 0: zout = bf16(z + c1*f)   ; S = z + c2*f
// mode 1: zout = bf16(znb + c1*f) ; S += c2*f
// mode 2: zout = bf16(S + c2*f)
// mode 3: out(f32, first 128 cols) = S + c2*f   (final eval; no zout write)
__global__ __launch_bounds__(256, 8) void k_eval(
    const uint16_t* __restrict__ zsrc, const uint16_t* __restrict__ znb,
    uint16_t* __restrict__ zout, float* __restrict__ S, float* __restrict__ out,
    const uint16_t* __restrict__ az, const uint16_t* __restrict__ Mpk,
    const float* __restrict__ x, const float* __restrict__ alph,
    int N, int mode, float c1, float c2)
{
    __shared__ uint16_t gs[32][264];   // z@M result, bf16  ~16.9 KB
    __shared__ float alph_s[32];

    int t = threadIdx.x;
    int r0 = blockIdx.x * 32;
    int wv = t >> 6;
    int lane = t & 63;

    if (t < 32) alph_s[t] = (r0 + t < N) ? alph[r0 + t] : 0.f;

    // P1: A fragments straight from global (block slab = 16KB, cache-resident)
    int m = lane & 15, quad = lane >> 4;
    int half = wv & 1, whichW = wv >> 1;
    int arow = half * 16 + m;
    int garow = r0 + arow;
    bool rowok = garow < N;
    short8 afr[8];
    #pragma unroll
    for (int kt = 0; kt < 8; kt++)
        afr[kt] = rowok ? *(const short8*)(zsrc + (size_t)garow * 256 + kt * 32 + quad * 8)
                        : short8{0, 0, 0, 0, 0, 0, 0, 0};

    // P2: MFMA over 8 column tiles; results to LDS in bf16
    int lrb = half * 16 + quad * 4;
    #pragma unroll
    for (int nt = 0; nt < 8; nt++) {
        int tile = whichW * 8 + nt;
        f32x4 acc = {0.f, 0.f, 0.f, 0.f};
        #pragma unroll
        for (int kt = 0; kt < 8; kt++) {
            short8 b = ((const short8*)Mpk)[(tile * 8 + kt) * 64 + lane];
            acc = __builtin_amdgcn_mfma_f32_16x16x32_bf16(afr[kt], b, acc, 0, 0, 0);
        }
        int gcol = tile * 16 + m;
        #pragma unroll
        for (int r = 0; r < 4; r++)
            gs[lrb + r][gcol] = (uint16_t)f2bf(acc[r]);
    }
    __syncthreads();

    // P3: coalesced combine + RK4 (pure float4/ushort4 streams)
    #pragma unroll
    for (int i = 0; i < 8; i++) {
        int idx = t + i * 256;
        int row = idx >> 6, c4 = idx & 63;
        int grow = r0 + row;
        if (grow >= N) continue;
        size_t b4 = (size_t)grow * 64 + c4;
        float al = alph_s[row];
        ushort4 a4 = ((const ushort4*)az)[b4];
        ushort4 z4 = ((const ushort4*)zsrc)[b4];
        ushort4 g4 = *(const ushort4*)&gs[row][c4 * 4];
        float4 x4 = make_float4(0.f, 0.f, 0.f, 0.f);
        if (c4 < 32) x4 = ((const float4*)x)[(size_t)grow * 32 + c4];
        float zv0 = bf2f(z4.x), zv1 = bf2f(z4.y), zv2 = bf2f(z4.z), zv3 = bf2f(z4.w);
        float f0 = al * (bf2f(a4.x) - zv0) + bf2f(g4.x) + x4.x;
        float f1 = al * (bf2f(a4.y) - zv1) + bf2f(g4.y) + x4.y;
        float f2 = al * (bf2f(a4.z) - zv2) + bf2f(g4.z) + x4.z;
        float f3 = al * (bf2f(a4.w) - zv3) + bf2f(g4.w) + x4.w;
        if (mode == 0) {
            ushort4 o;
            o.x = (uint16_t)f2bf(zv0 + c1 * f0); o.y = (uint16_t)f2bf(zv1 + c1 * f1);
            o.z = (uint16_t)f2bf(zv2 + c1 * f2); o.w = (uint16_t)f2bf(zv3 + c1 * f3);
            ((ushort4*)zout)[b4] = o;
            float4 s4;
            s4.x = zv0 + c2 * f0; s4.y = zv1 + c2 * f1;
            s4.z = zv2 + c2 * f2; s4.w = zv3 + c2 * f3;
            ((float4*)S)[b4] = s4;
        } else if (mode == 1) {
            ushort4 zb = ((const ushort4*)znb)[b4];
            ushort4 o;
            o.x = (uint16_t)f2bf(bf2f(zb.x) + c1 * f0);
            o.y = (uint16_t)f2bf(bf2f(zb.y) + c1 * f1);
            o.z = (uint16_t)f2bf(bf2f(zb.z) + c1 * f2);
            o.w = (uint16_t)f2bf(bf2f(zb.w) + c1 * f3);
            ((ushort4*)zout)[b4] = o;
            float4 s4 = ((const float4*)S)[b4];
            s4.x += c2 * f0; s4.y += c2 * f1; s4.z += c2 * f2; s4.w += c2 * f3;
            ((float4*)S)[b4] = s4;
        } else if (mode == 2) {
            float4 s4 = ((const float4*)S)[b4];
            ushort4 o;
            o.x = (uint16_t)f2bf(s4.x + c2 * f0); o.y = (uint16_t)f2bf(s4.y + c2 * f1);
            o.z = (uint16_t)f2bf(s4.z + c2 * f2); o.w = (uint16_t)f2bf(s4.w + c2 * f3);
            ((ushort4*)zout)[b4] = o;
        } else {
            if (c4 < 32) {
                float4 s4 = ((const float4*)S)[b4];
                float4 o;
                o.x = s4.x + c2 * f0; o.y = s4.y + c2 * f1;
                o.z = s4.z + c2 * f2; o.w = s4.w + c2 * f3;
                ((float4*)out)[(size_t)grow * 32 + c4] = o;
            }
        }
    }
}

__global__ void k_fill(float* __restrict__ out, int n, float v) {
    int idx = blockIdx.x * blockDim.x + threadIdx.x;
    if (idx < n) out[idx] = v;
}

static inline size_t alignup(size_t v) { return (v + 255) & ~(size_t)255; }

extern "C" void kernel_launch(void* const* d_in, const int* in_sizes, int n_in,
                              void* d_out, int out_size, void* d_ws, size_t ws_size,
                              hipStream_t stream) {
    const float* x      = (const float*)d_in[0];
    const int*   erow   = (const int*)d_in[1];
    const int*   ecol   = (const int*)d_in[2];
    const float* evals  = (const float*)d_in[3];
    const float* W_ih   = (const float*)d_in[4];
    const float* W_hh   = (const float*)d_in[5];
    const float* b_ih   = (const float*)d_in[6];
    const float* b_hh   = (const float*)d_in[7];
    const float* h      = (const float*)d_in[8];
    const float* alpha0 = (const float*)d_in[9];
    const float* W      = (const float*)d_in[10];
    const float* dvec   = (const float*)d_in[11];

    int N = in_sizes[0] / DINF;
    int E = in_sizes[1];

    char* w = (char*)d_ws;
    uint16_t* znb = (uint16_t*)w; w += alignup((size_t)N * DD * 2);   //  51.2 MB
    float* S  = (float*)w;        w += alignup((size_t)N * DD * 4);   // 102.4 MB
    uint16_t* zpA = (uint16_t*)w; w += alignup((size_t)N * DD * 2);   //  51.2 MB
    uint16_t* az = (uint16_t*)w;  w += alignup((size_t)N * DD * 2);   //  51.2 MB
    float* alpha = (float*)w;     w += alignup((size_t)N * 4);
    float* alph = (float*)w;      w += alignup((size_t)N * 4);
    uint16_t* Mpk = (uint16_t*)w; w += alignup((size_t)DD * DD * 2);
    int* counts = (int*)w;        w += alignup((size_t)(N + 1) * 4);  // reused as cursor
    int* row_ptr = (int*)w;       w += alignup((size_t)(N + 1) * 4);
    int* blksum = (int*)w;        w += alignup((size_t)1024 * 4);
    int* cols_s = (int*)w;        w += alignup((size_t)E * 4);
    float* vals_s = (float*)w;    w += alignup((size_t)E * 4);
    size_t need = (size_t)(w - (char*)d_ws);   // ~264 MB

    // zpB (bf16 ping-pong partner) lives in d_out; its last read (eval3 of step 2)
    // precedes the final mode-3 eval that overwrites d_out with the fp32 result.
    uint16_t* zpB = (uint16_t*)d_out;

    if (ws_size < need) {
        k_fill<<<(out_size + 255) / 256, 256, 0, stream>>>((float*)d_out, out_size, 1000.0f);
        return;
    }

    int n1 = N + 1, nb = (n1 + 1023) / 1024;
    hipMemsetAsync(counts, 0, (size_t)n1 * 4, stream);
    k_hist<<<(E + 255) / 256, 256, 0, stream>>>(erow, counts, E);
    k_scan1<<<nb, 1024, 0, stream>>>(counts, row_ptr, blksum, n1);
    k_scan2<<<1, 1024, 0, stream>>>(blksum, nb);
    k_scan3<<<(n1 + 255) / 256, 256, 0, stream>>>(blksum, row_ptr, counts, n1);
    k_scatter<<<(E + 255) / 256, 256, 0, stream>>>(erow, ecol, evals, counts, cols_s, vals_s, E);

    k_build_m<<<DD, DD, 0, stream>>>(W, dvec, Mpk);
    k_init<<<(N * 64 + 255) / 256, 256, 0, stream>>>(x, alpha0, znb, alpha, N);

    const float dt = 0.45f;  // T_END / N_STEPS
    int nwaves = (N + RPW - 1) / RPW;
    int gsmm = (int)(((size_t)nwaves * 64 + 255) / 256);
    int ge = (N + 31) / 32;
    for (int s = 0; s < 2; s++) {
        // eval1: z = znb -> eval point zpA
        k_spmm<<<gsmm, 256, 0, stream>>>(znb, row_ptr, cols_s, vals_s, W_ih, W_hh,
                                         b_ih, b_hh, h, alpha, alph, az, N);
        k_eval<<<ge, 256, 0, stream>>>(znb, znb, zpA, S, nullptr, az, Mpk, x, alph,
                                       N, 0, 0.5f * dt, dt / 6.f);
        // eval2: z = zpA -> zpB
        k_spmm<<<gsmm, 256, 0, stream>>>(zpA, row_ptr, cols_s, vals_s, W_ih, W_hh,
                                         b_ih, b_hh, h, alpha, alph, az, N);
        k_eval<<<ge, 256, 0, stream>>>(zpA, znb, zpB, S, nullptr, az, Mpk, x, alph,
                                       N, 1, 0.5f * dt, dt / 3.f);
        // eval3: z = zpB -> zpA
        k_spmm<<<gsmm, 256, 0, stream>>>(zpB, row_ptr, cols_s, vals_s, W_ih, W_hh,
                                         b_ih, b_hh, h, alpha, alph, az, N);
        k_eval<<<ge, 256, 0, stream>>>(zpB, znb, zpA, S, nullptr, az, Mpk, x, alph,
                                       N, 1, dt, dt / 3.f);
        // eval4
        k_spmm<<<gsmm, 256, 0, stream>>>(zpA, row_ptr, cols_s, vals_s, W_ih, W_hh,
                                         b_ih, b_hh, h, alpha, alph, az, N);
        if (s == 0) {
            k_eval<<<ge, 256, 0, stream>>>(zpA, znb, znb, S, nullptr, az, Mpk, x, alph,
                                           N, 2, 0.f, dt / 6.f);
        } else {
            // final eval: emit fp32 output directly (first 128 cols)
            k_eval<<<ge, 256, 0, stream>>>(zpA, znb, znb, S, (float*)d_out, az, Mpk, x, alph,
                                           N, 3, 0.f, dt / 6.f);
        }
    }
}

// Round 4
// 1738.085 us; speedup vs baseline: 1.2493x; 1.1443x over previous
//
#include <hip/hip_runtime.h>
#include <stdint.h>

#define DD 256
#define DINF 128

typedef __attribute__((ext_vector_type(8))) short short8;
typedef __attribute__((ext_vector_type(4))) float f32x4;

__device__ __forceinline__ short f2bf(float f) {
    union { float f; uint32_t u; } c{f};
    uint32_t r = (c.u + 0x7fffu + ((c.u >> 16) & 1u)) >> 16;
    return (short)(uint16_t)r;
}

__device__ __forceinline__ float bf2f(uint16_t b) {
    union { uint32_t u; float f; } c;
    c.u = ((uint32_t)b) << 16;
    return c.f;
}

// ---------------- CSR build ----------------
__global__ void k_hist(const int* __restrict__ rows, int* __restrict__ counts, int E) {
    int e = blockIdx.x * blockDim.x + threadIdx.x;
    if (e < E) atomicAdd(&counts[rows[e] + 1], 1);
}

__global__ void k_scan1(const int* __restrict__ counts, int* __restrict__ part,
                        int* __restrict__ blksum, int n1) {
    __shared__ int tmp[1024];
    int b = blockIdx.x, t = threadIdx.x, i = b * 1024 + t;
    int v = (i < n1) ? counts[i] : 0;
    tmp[t] = v;
    __syncthreads();
    for (int off = 1; off < 1024; off <<= 1) {
        int a = (t >= off) ? tmp[t - off] : 0;
        __syncthreads();
        tmp[t] += a;
        __syncthreads();
    }
    if (i < n1) part[i] = tmp[t];
    if (t == 1023) blksum[b] = tmp[t];
}

__global__ void k_scan2(int* __restrict__ blksum, int nb) {
    __shared__ int tmp[1024];
    int t = threadIdx.x;
    int v = (t < nb) ? blksum[t] : 0;
    tmp[t] = v;
    __syncthreads();
    for (int off = 1; off < 1024; off <<= 1) {
        int a = (t >= off) ? tmp[t - off] : 0;
        __syncthreads();
        tmp[t] += a;
        __syncthreads();
    }
    if (t < nb) blksum[t] = tmp[t];
}

__global__ void k_scan3(const int* __restrict__ blksum, int* __restrict__ row_ptr,
                        int* __restrict__ cursor, int n1) {
    int i = blockIdx.x * blockDim.x + threadIdx.x;
    if (i < n1) {
        int b = i >> 10;
        int off = (b > 0) ? blksum[b - 1] : 0;
        int v = row_ptr[i] + off;
        row_ptr[i] = v;
        cursor[i] = v;
    }
}

__global__ void k_scatter(const int* __restrict__ rows, const int* __restrict__ cols,
                          const float* __restrict__ vals, int* __restrict__ cursor,
                          int* __restrict__ cols_s, float* __restrict__ vals_s, int E) {
    int e = blockIdx.x * blockDim.x + threadIdx.x;
    if (e < E) {
        int r = rows[e];
        int pos = atomicAdd(&cursor[r], 1);
        cols_s[pos] = cols[e];
        vals_s[pos] = vals[e];
    }
}

// ---------------- M = (W*clip(d))@W^T - I, packed in MFMA B-fragment order ----------------
__global__ void k_build_m(const float* __restrict__ W, const float* __restrict__ dvec,
                          uint16_t* __restrict__ Mpk) {
    __shared__ float u[DD];
    int n = blockIdx.x, k = threadIdx.x;
    float dj = dvec[k];
    dj = fminf(fmaxf(dj, 0.f), 1.f);
    u[k] = W[n * DD + k] * dj;
    __syncthreads();
    float acc = 0.f;
    for (int j = 0; j < DD; j++) acc += u[j] * W[k * DD + j];
    acc -= (n == k) ? 1.f : 0.f;
    int tile = n >> 4, m = n & 15, kt = k >> 5, quad = (k >> 3) & 3, j = k & 7;
    int lane = quad * 16 + m;
    Mpk[(((tile * 8 + kt) * 64 + lane) << 3) + j] = (uint16_t)f2bf(acc);
}

// ---------------- init: znb = bf16([x,0]), alpha = alpha0 ----------------
__global__ void k_init(const float* __restrict__ x, const float* __restrict__ alpha0,
                       uint16_t* __restrict__ znb, float* __restrict__ alpha, int N) {
    int idx = blockIdx.x * blockDim.x + threadIdx.x;
    int total = N * 64;
    if (idx < total) {
        int row = idx >> 6, c4 = idx & 63;
        float4 v = make_float4(0.f, 0.f, 0.f, 0.f);
        if (c4 < 32) v = ((const float4*)x)[(size_t)row * 32 + c4];
        ushort4 b;
        b.x = (uint16_t)f2bf(v.x); b.y = (uint16_t)f2bf(v.y);
        b.z = (uint16_t)f2bf(v.z); b.w = (uint16_t)f2bf(v.w);
        ((ushort4*)znb)[idx] = b;
    }
    if (idx < N) alpha[idx] = alpha0[idx];
}

// ---------------- SpMM + alpha: one row per wave, 2-deep pipelined gather ----------
// az = bf16(A*z); alpha update; alph = 0.5*sigmoid(alpha)
__global__ void k_spmm(const uint16_t* __restrict__ z, const int* __restrict__ row_ptr,
                       const int* __restrict__ cols_s, const float* __restrict__ vals_s,
                       const float* __restrict__ W_ih, const float* __restrict__ W_hh,
                       const float* __restrict__ b_ih, const float* __restrict__ b_hh,
                       const float* __restrict__ hbuf, float* __restrict__ alpha,
                       float* __restrict__ alph, uint16_t* __restrict__ az, int N) {
    int wave = (int)((blockIdx.x * (size_t)blockDim.x + threadIdx.x) >> 6);
    int lane = threadIdx.x & 63;
    if (wave >= N) return;

    // own-row eval point (cols 4*lane..+3)
    ushort4 zr4 = ((const ushort4*)z)[(size_t)wave * 64 + lane];
    float z0 = bf2f(zr4.x), z1 = bf2f(zr4.y), z2 = bf2f(zr4.z), z3 = bf2f(zr4.w);

    // RNNCell dot partials
    float4 w0 = ((const float4*)W_ih)[lane];
    float4 w1 = ((const float4*)(W_ih + DD))[lane];
    float s0 = z0 * w0.x + z1 * w0.y + z2 * w0.z + z3 * w0.w;
    float s1 = z0 * w1.x + z1 * w1.y + z2 * w1.z + z3 * w1.w;

    // gather, 2-deep software pipeline: z-row load for edge i+1 issues before
    // edge i's row is consumed -> two 512B row fetches in flight per wave.
    int s = row_ptr[wave], e = row_ptr[wave + 1];
    float4 acc = make_float4(0.f, 0.f, 0.f, 0.f);
    float v0 = 0.f, v1 = 0.f;
    int c1 = 0;
    ushort4 zr0 = make_ushort4(0, 0, 0, 0);
    if (s < e) {
        int c0 = cols_s[s];
        v0 = vals_s[s];
        zr0 = ((const ushort4*)z)[(size_t)c0 * 64 + lane];
    }
    if (s + 1 < e) { c1 = cols_s[s + 1]; v1 = vals_s[s + 1]; }
    for (int i = s; i < e; i++) {
        ushort4 zr1 = make_ushort4(0, 0, 0, 0);
        if (i + 1 < e) zr1 = ((const ushort4*)z)[(size_t)c1 * 64 + lane];
        int c2 = 0; float v2 = 0.f;
        if (i + 2 < e) { c2 = cols_s[i + 2]; v2 = vals_s[i + 2]; }
        acc.x += v0 * bf2f(zr0.x); acc.y += v0 * bf2f(zr0.y);
        acc.z += v0 * bf2f(zr0.z); acc.w += v0 * bf2f(zr0.w);
        zr0 = zr1; v0 = v1; c1 = c2; v1 = v2;
    }
    ushort4 o;
    o.x = (uint16_t)f2bf(acc.x); o.y = (uint16_t)f2bf(acc.y);
    o.z = (uint16_t)f2bf(acc.z); o.w = (uint16_t)f2bf(acc.w);
    ((ushort4*)az)[(size_t)wave * 64 + lane] = o;

    // wave-reduce the dots, lane 0 does the alpha update
    #pragma unroll
    for (int off = 32; off >= 1; off >>= 1) {
        s0 += __shfl_down(s0, off, 64);
        s1 += __shfl_down(s1, off, 64);
    }
    if (lane == 0) {
        float h0 = hbuf[wave * 2], h1 = hbuf[wave * 2 + 1];
        float cc0 = b_ih[0] + b_hh[0] + h0 * W_hh[0] + h1 * W_hh[1];
        float cc1 = b_ih[1] + b_hh[1] + h0 * W_hh[2] + h1 * W_hh[3];
        float anew = alpha[wave] * tanhf(s0 + cc0) + tanhf(s1 + cc1);
        alpha[wave] = anew;
        alph[wave] = 0.5f / (1.f + expf(-anew));
    }
}

// ---------------- eval: z@M (MFMA) + combine + RK4 ----------------
// f = alph*(az - z) + z@M + x0
// A-fragments and P3 z-values read directly from global zsrc (L1/L2-hot 16KB slab);
// only the MFMA result gs lives in LDS -> 17 KB -> 8 blocks/CU.
// mode 0: zout = bf16(z + c1*f)   ; S = z + c2*f
// mode 1: zout = bf16(znb + c1*f) ; S += c2*f
// mode 2: zout = bf16(S + c2*f)
// mode 3: out(f32, first 128 cols) = S + c2*f   (final eval; no zout write)
__global__ __launch_bounds__(256, 8) void k_eval(
    const uint16_t* __restrict__ zsrc, const uint16_t* __restrict__ znb,
    uint16_t* __restrict__ zout, float* __restrict__ S, float* __restrict__ out,
    const uint16_t* __restrict__ az, const uint16_t* __restrict__ Mpk,
    const float* __restrict__ x, const float* __restrict__ alph,
    int N, int mode, float c1, float c2)
{
    __shared__ uint16_t gs[32][264];   // z@M result, bf16  ~16.9 KB
    __shared__ float alph_s[32];

    int t = threadIdx.x;
    int r0 = blockIdx.x * 32;
    int wv = t >> 6;
    int lane = t & 63;

    if (t < 32) alph_s[t] = (r0 + t < N) ? alph[r0 + t] : 0.f;

    // P1: A fragments straight from global (block slab = 16KB, cache-resident)
    int m = lane & 15, quad = lane >> 4;
    int half = wv & 1, whichW = wv >> 1;
    int arow = half * 16 + m;
    int garow = r0 + arow;
    bool rowok = garow < N;
    short8 afr[8];
    #pragma unroll
    for (int kt = 0; kt < 8; kt++)
        afr[kt] = rowok ? *(const short8*)(zsrc + (size_t)garow * 256 + kt * 32 + quad * 8)
                        : short8{0, 0, 0, 0, 0, 0, 0, 0};

    // P2: MFMA over 8 column tiles; results to LDS in bf16
    int lrb = half * 16 + quad * 4;
    #pragma unroll
    for (int nt = 0; nt < 8; nt++) {
        int tile = whichW * 8 + nt;
        f32x4 acc = {0.f, 0.f, 0.f, 0.f};
        #pragma unroll
        for (int kt = 0; kt < 8; kt++) {
            short8 b = ((const short8*)Mpk)[(tile * 8 + kt) * 64 + lane];
            acc = __builtin_amdgcn_mfma_f32_16x16x32_bf16(afr[kt], b, acc, 0, 0, 0);
        }
        int gcol = tile * 16 + m;
        #pragma unroll
        for (int r = 0; r < 4; r++)
            gs[lrb + r][gcol] = (uint16_t)f2bf(acc[r]);
    }
    __syncthreads();

    // P3: coalesced combine + RK4 (pure float4/ushort4 streams)
    #pragma unroll
    for (int i = 0; i < 8; i++) {
        int idx = t + i * 256;
        int row = idx >> 6, c4 = idx & 63;
        int grow = r0 + row;
        if (grow >= N) continue;
        size_t b4 = (size_t)grow * 64 + c4;
        float al = alph_s[row];
        ushort4 a4 = ((const ushort4*)az)[b4];
        ushort4 z4 = ((const ushort4*)zsrc)[b4];
        ushort4 g4 = *(const ushort4*)&gs[row][c4 * 4];
        float4 x4 = make_float4(0.f, 0.f, 0.f, 0.f);
        if (c4 < 32) x4 = ((const float4*)x)[(size_t)grow * 32 + c4];
        float zv0 = bf2f(z4.x), zv1 = bf2f(z4.y), zv2 = bf2f(z4.z), zv3 = bf2f(z4.w);
        float f0 = al * (bf2f(a4.x) - zv0) + bf2f(g4.x) + x4.x;
        float f1 = al * (bf2f(a4.y) - zv1) + bf2f(g4.y) + x4.y;
        float f2 = al * (bf2f(a4.z) - zv2) + bf2f(g4.z) + x4.z;
        float f3 = al * (bf2f(a4.w) - zv3) + bf2f(g4.w) + x4.w;
        if (mode == 0) {
            ushort4 o;
            o.x = (uint16_t)f2bf(zv0 + c1 * f0); o.y = (uint16_t)f2bf(zv1 + c1 * f1);
            o.z = (uint16_t)f2bf(zv2 + c1 * f2); o.w = (uint16_t)f2bf(zv3 + c1 * f3);
            ((ushort4*)zout)[b4] = o;
            float4 s4;
            s4.x = zv0 + c2 * f0; s4.y = zv1 + c2 * f1;
            s4.z = zv2 + c2 * f2; s4.w = zv3 + c2 * f3;
            ((float4*)S)[b4] = s4;
        } else if (mode == 1) {
            ushort4 zb = ((const ushort4*)znb)[b4];
            ushort4 o;
            o.x = (uint16_t)f2bf(bf2f(zb.x) + c1 * f0);
            o.y = (uint16_t)f2bf(bf2f(zb.y) + c1 * f1);
            o.z = (uint16_t)f2bf(bf2f(zb.z) + c1 * f2);
            o.w = (uint16_t)f2bf(bf2f(zb.w) + c1 * f3);
            ((ushort4*)zout)[b4] = o;
            float4 s4 = ((const float4*)S)[b4];
            s4.x += c2 * f0; s4.y += c2 * f1; s4.z += c2 * f2; s4.w += c2 * f3;
            ((float4*)S)[b4] = s4;
        } else if (mode == 2) {
            float4 s4 = ((const float4*)S)[b4];
            ushort4 o;
            o.x = (uint16_t)f2bf(s4.x + c2 * f0); o.y = (uint16_t)f2bf(s4.y + c2 * f1);
            o.z = (uint16_t)f2bf(s4.z + c2 * f2); o.w = (uint16_t)f2bf(s4.w + c2 * f3);
            ((ushort4*)zout)[b4] = o;
        } else {
            if (c4 < 32) {
                float4 s4 = ((const float4*)S)[b4];
                float4 o;
                o.x = s4.x + c2 * f0; o.y = s4.y + c2 * f1;
                o.z = s4.z + c2 * f2; o.w = s4.w + c2 * f3;
                ((float4*)out)[(size_t)grow * 32 + c4] = o;
            }
        }
    }
}

__global__ void k_fill(float* __restrict__ out, int n, float v) {
    int idx = blockIdx.x * blockDim.x + threadIdx.x;
    if (idx < n) out[idx] = v;
}

static inline size_t alignup(size_t v) { return (v + 255) & ~(size_t)255; }

extern "C" void kernel_launch(void* const* d_in, const int* in_sizes, int n_in,
                              void* d_out, int out_size, void* d_ws, size_t ws_size,
                              hipStream_t stream) {
    const float* x      = (const float*)d_in[0];
    const int*   erow   = (const int*)d_in[1];
    const int*   ecol   = (const int*)d_in[2];
    const float* evals  = (const float*)d_in[3];
    const float* W_ih   = (const float*)d_in[4];
    const float* W_hh   = (const float*)d_in[5];
    const float* b_ih   = (const float*)d_in[6];
    const float* b_hh   = (const float*)d_in[7];
    const float* h      = (const float*)d_in[8];
    const float* alpha0 = (const float*)d_in[9];
    const float* W      = (const float*)d_in[10];
    const float* dvec   = (const float*)d_in[11];

    int N = in_sizes[0] / DINF;
    int E = in_sizes[1];

    char* w = (char*)d_ws;
    uint16_t* znb = (uint16_t*)w; w += alignup((size_t)N * DD * 2);   //  51.2 MB
    float* S  = (float*)w;        w += alignup((size_t)N * DD * 4);   // 102.4 MB
    uint16_t* zpA = (uint16_t*)w; w += alignup((size_t)N * DD * 2);   //  51.2 MB
    uint16_t* az = (uint16_t*)w;  w += alignup((size_t)N * DD * 2);   //  51.2 MB
    float* alpha = (float*)w;     w += alignup((size_t)N * 4);
    float* alph = (float*)w;      w += alignup((size_t)N * 4);
    uint16_t* Mpk = (uint16_t*)w; w += alignup((size_t)DD * DD * 2);
    int* counts = (int*)w;        w += alignup((size_t)(N + 1) * 4);  // reused as cursor
    int* row_ptr = (int*)w;       w += alignup((size_t)(N + 1) * 4);
    int* blksum = (int*)w;        w += alignup((size_t)1024 * 4);
    int* cols_s = (int*)w;        w += alignup((size_t)E * 4);
    float* vals_s = (float*)w;    w += alignup((size_t)E * 4);
    size_t need = (size_t)(w - (char*)d_ws);   // ~264 MB

    // zpB (bf16 ping-pong partner) lives in d_out; its last read (eval3 of step 2)
    // precedes the final mode-3 eval that overwrites d_out with the fp32 result.
    uint16_t* zpB = (uint16_t*)d_out;

    if (ws_size < need) {
        k_fill<<<(out_size + 255) / 256, 256, 0, stream>>>((float*)d_out, out_size, 1000.0f);
        return;
    }

    int n1 = N + 1, nb = (n1 + 1023) / 1024;
    hipMemsetAsync(counts, 0, (size_t)n1 * 4, stream);
    k_hist<<<(E + 255) / 256, 256, 0, stream>>>(erow, counts, E);
    k_scan1<<<nb, 1024, 0, stream>>>(counts, row_ptr, blksum, n1);
    k_scan2<<<1, 1024, 0, stream>>>(blksum, nb);
    k_scan3<<<(n1 + 255) / 256, 256, 0, stream>>>(blksum, row_ptr, counts, n1);
    k_scatter<<<(E + 255) / 256, 256, 0, stream>>>(erow, ecol, evals, counts, cols_s, vals_s, E);

    k_build_m<<<DD, DD, 0, stream>>>(W, dvec, Mpk);
    k_init<<<(N * 64 + 255) / 256, 256, 0, stream>>>(x, alpha0, znb, alpha, N);

    const float dt = 0.45f;  // T_END / N_STEPS
    int gs = (N + 3) / 4, ge = (N + 31) / 32;
    for (int s = 0; s < 2; s++) {
        // eval1: z = znb -> eval point zpA
        k_spmm<<<gs, 256, 0, stream>>>(znb, row_ptr, cols_s, vals_s, W_ih, W_hh,
                                       b_ih, b_hh, h, alpha, alph, az, N);
        k_eval<<<ge, 256, 0, stream>>>(znb, znb, zpA, S, nullptr, az, Mpk, x, alph,
                                       N, 0, 0.5f * dt, dt / 6.f);
        // eval2: z = zpA -> zpB
        k_spmm<<<gs, 256, 0, stream>>>(zpA, row_ptr, cols_s, vals_s, W_ih, W_hh,
                                       b_ih, b_hh, h, alpha, alph, az, N);
        k_eval<<<ge, 256, 0, stream>>>(zpA, znb, zpB, S, nullptr, az, Mpk, x, alph,
                                       N, 1, 0.5f * dt, dt / 3.f);
        // eval3: z = zpB -> zpA
        k_spmm<<<gs, 256, 0, stream>>>(zpB, row_ptr, cols_s, vals_s, W_ih, W_hh,
                                       b_ih, b_hh, h, alpha, alph, az, N);
        k_eval<<<ge, 256, 0, stream>>>(zpB, znb, zpA, S, nullptr, az, Mpk, x, alph,
                                       N, 1, dt, dt / 3.f);
        // eval4
        k_spmm<<<gs, 256, 0, stream>>>(zpA, row_ptr, cols_s, vals_s, W_ih, W_hh,
                                       b_ih, b_hh, h, alpha, alph, az, N);
        if (s == 0) {
            k_eval<<<ge, 256, 0, stream>>>(zpA, znb, znb, S, nullptr, az, Mpk, x, alph,
                                           N, 2, 0.f, dt / 6.f);
        } else {
            // final eval: emit fp32 output directly (first 128 cols)
            k_eval<<<ge, 256, 0, stream>>>(zpA, znb, znb, S, (float*)d_out, az, Mpk, x, alph,
                                           N, 3, 0.f, dt / 6.f);
        }
    }
}

// Round 5
// 1556.845 us; speedup vs baseline: 1.3947x; 1.1164x over previous
//
#include <hip/hip_runtime.h>
#include <stdint.h>

#define DD 256
#define DINF 128

typedef __attribute__((ext_vector_type(8))) short short8;
typedef __attribute__((ext_vector_type(4))) float f32x4;

__device__ __forceinline__ short f2bf(float f) {
    union { float f; uint32_t u; } c{f};
    uint32_t r = (c.u + 0x7fffu + ((c.u >> 16) & 1u)) >> 16;
    return (short)(uint16_t)r;
}

__device__ __forceinline__ float bf2f(uint16_t b) {
    union { uint32_t u; float f; } c;
    c.u = ((uint32_t)b) << 16;
    return c.f;
}

// ---------------- CSR build ----------------
__global__ void k_hist(const int* __restrict__ rows, int* __restrict__ counts, int E) {
    int e = blockIdx.x * blockDim.x + threadIdx.x;
    if (e < E) atomicAdd(&counts[rows[e] + 1], 1);
}

__global__ void k_scan1(const int* __restrict__ counts, int* __restrict__ part,
                        int* __restrict__ blksum, int n1) {
    __shared__ int tmp[1024];
    int b = blockIdx.x, t = threadIdx.x, i = b * 1024 + t;
    int v = (i < n1) ? counts[i] : 0;
    tmp[t] = v;
    __syncthreads();
    for (int off = 1; off < 1024; off <<= 1) {
        int a = (t >= off) ? tmp[t - off] : 0;
        __syncthreads();
        tmp[t] += a;
        __syncthreads();
    }
    if (i < n1) part[i] = tmp[t];
    if (t == 1023) blksum[b] = tmp[t];
}

__global__ void k_scan2(int* __restrict__ blksum, int nb) {
    __shared__ int tmp[1024];
    int t = threadIdx.x;
    int v = (t < nb) ? blksum[t] : 0;
    tmp[t] = v;
    __syncthreads();
    for (int off = 1; off < 1024; off <<= 1) {
        int a = (t >= off) ? tmp[t - off] : 0;
        __syncthreads();
        tmp[t] += a;
        __syncthreads();
    }
    if (t < nb) blksum[t] = tmp[t];
}

__global__ void k_scan3(const int* __restrict__ blksum, int* __restrict__ row_ptr,
                        int* __restrict__ cursor, int n1) {
    int i = blockIdx.x * blockDim.x + threadIdx.x;
    if (i < n1) {
        int b = i >> 10;
        int off = (b > 0) ? blksum[b - 1] : 0;
        int v = row_ptr[i] + off;
        row_ptr[i] = v;
        cursor[i] = v;
    }
}

__global__ void k_scatter(const int* __restrict__ rows, const int* __restrict__ cols,
                          const float* __restrict__ vals, int* __restrict__ cursor,
                          int* __restrict__ cols_s, float* __restrict__ vals_s, int E) {
    int e = blockIdx.x * blockDim.x + threadIdx.x;
    if (e < E) {
        int r = rows[e];
        int pos = atomicAdd(&cursor[r], 1);
        cols_s[pos] = cols[e];
        vals_s[pos] = vals[e];
    }
}

// ---------------- M = (W*clip(d))@W^T - I, packed in MFMA B-fragment order ----------------
__global__ void k_build_m(const float* __restrict__ W, const float* __restrict__ dvec,
                          uint16_t* __restrict__ Mpk) {
    __shared__ float u[DD];
    int n = blockIdx.x, k = threadIdx.x;
    float dj = dvec[k];
    dj = fminf(fmaxf(dj, 0.f), 1.f);
    u[k] = W[n * DD + k] * dj;
    __syncthreads();
    float acc = 0.f;
    for (int j = 0; j < DD; j++) acc += u[j] * W[k * DD + j];
    acc -= (n == k) ? 1.f : 0.f;
    int tile = n >> 4, m = n & 15, kt = k >> 5, quad = (k >> 3) & 3, j = k & 7;
    int lane = quad * 16 + m;
    Mpk[(((tile * 8 + kt) * 64 + lane) << 3) + j] = (uint16_t)f2bf(acc);
}

// ---------------- init: znb = bf16([x,0]), alpha = alpha0 ----------------
__global__ void k_init(const float* __restrict__ x, const float* __restrict__ alpha0,
                       uint16_t* __restrict__ znb, float* __restrict__ alpha, int N) {
    int idx = blockIdx.x * blockDim.x + threadIdx.x;
    int total = N * 64;
    if (idx < total) {
        int row = idx >> 6, c4 = idx & 63;
        float4 v = make_float4(0.f, 0.f, 0.f, 0.f);
        if (c4 < 32) v = ((const float4*)x)[(size_t)row * 32 + c4];
        ushort4 b;
        b.x = (uint16_t)f2bf(v.x); b.y = (uint16_t)f2bf(v.y);
        b.z = (uint16_t)f2bf(v.z); b.w = (uint16_t)f2bf(v.w);
        ((ushort4*)znb)[idx] = b;
    }
    if (idx < N) alpha[idx] = alpha0[idx];
}

// ---------------- SpMM + alpha: one row per wave, chunk-of-4 gather ----------
// az = bf16(A*z); alpha update; alph = 0.5*sigmoid(alpha)
__global__ void k_spmm(const uint16_t* __restrict__ z, const int* __restrict__ row_ptr,
                       const int* __restrict__ cols_s, const float* __restrict__ vals_s,
                       const float* __restrict__ W_ih, const float* __restrict__ W_hh,
                       const float* __restrict__ b_ih, const float* __restrict__ b_hh,
                       const float* __restrict__ hbuf, float* __restrict__ alpha,
                       float* __restrict__ alph, uint16_t* __restrict__ az, int N) {
    int wave = (int)((blockIdx.x * (size_t)blockDim.x + threadIdx.x) >> 6);
    int lane = threadIdx.x & 63;
    if (wave >= N) return;

    // own-row eval point (cols 4*lane..+3)
    ushort4 zr4 = ((const ushort4*)z)[(size_t)wave * 64 + lane];
    float z0 = bf2f(zr4.x), z1 = bf2f(zr4.y), z2 = bf2f(zr4.z), z3 = bf2f(zr4.w);

    // RNNCell dot partials
    float4 w0 = ((const float4*)W_ih)[lane];
    float4 w1 = ((const float4*)(W_ih + DD))[lane];
    float s0 = z0 * w0.x + z1 * w0.y + z2 * w0.z + z3 * w0.w;
    float s1 = z0 * w1.x + z1 * w1.y + z2 * w1.z + z3 * w1.w;

    // gather in chunks of 4: 4 col/val loads then 4 independent 512B row
    // fetches in flight per chunk (branches are wave-uniform: degree is per-row)
    int s = row_ptr[wave], e = row_ptr[wave + 1];
    float4 acc = make_float4(0.f, 0.f, 0.f, 0.f);
    for (int i = s; i < e; i += 4) {
        int rem = e - i;
        int ca = cols_s[i];
        float va = vals_s[i];
        int cb = 0, cc = 0, cd = 0;
        float vb = 0.f, vc = 0.f, vd = 0.f;
        if (rem > 1) { cb = cols_s[i + 1]; vb = vals_s[i + 1]; }
        if (rem > 2) { cc = cols_s[i + 2]; vc = vals_s[i + 2]; }
        if (rem > 3) { cd = cols_s[i + 3]; vd = vals_s[i + 3]; }
        ushort4 ra = ((const ushort4*)z)[(size_t)ca * 64 + lane];
        ushort4 rb = (rem > 1) ? ((const ushort4*)z)[(size_t)cb * 64 + lane]
                               : make_ushort4(0, 0, 0, 0);
        ushort4 rc = (rem > 2) ? ((const ushort4*)z)[(size_t)cc * 64 + lane]
                               : make_ushort4(0, 0, 0, 0);
        ushort4 rd = (rem > 3) ? ((const ushort4*)z)[(size_t)cd * 64 + lane]
                               : make_ushort4(0, 0, 0, 0);
        acc.x += va * bf2f(ra.x) + vb * bf2f(rb.x) + vc * bf2f(rc.x) + vd * bf2f(rd.x);
        acc.y += va * bf2f(ra.y) + vb * bf2f(rb.y) + vc * bf2f(rc.y) + vd * bf2f(rd.y);
        acc.z += va * bf2f(ra.z) + vb * bf2f(rb.z) + vc * bf2f(rc.z) + vd * bf2f(rd.z);
        acc.w += va * bf2f(ra.w) + vb * bf2f(rb.w) + vc * bf2f(rc.w) + vd * bf2f(rd.w);
    }
    ushort4 o;
    o.x = (uint16_t)f2bf(acc.x); o.y = (uint16_t)f2bf(acc.y);
    o.z = (uint16_t)f2bf(acc.z); o.w = (uint16_t)f2bf(acc.w);
    ((ushort4*)az)[(size_t)wave * 64 + lane] = o;

    // wave-reduce the dots, lane 0 does the alpha update
    #pragma unroll
    for (int off = 32; off >= 1; off >>= 1) {
        s0 += __shfl_down(s0, off, 64);
        s1 += __shfl_down(s1, off, 64);
    }
    if (lane == 0) {
        float h0 = hbuf[wave * 2], h1 = hbuf[wave * 2 + 1];
        float cc0 = b_ih[0] + b_hh[0] + h0 * W_hh[0] + h1 * W_hh[1];
        float cc1 = b_ih[1] + b_hh[1] + h0 * W_hh[2] + h1 * W_hh[3];
        float anew = alpha[wave] * tanhf(s0 + cc0) + tanhf(s1 + cc1);
        alpha[wave] = anew;
        alph[wave] = 0.5f / (1.f + expf(-anew));
    }
}

// ---------------- eval: z@M (MFMA) + combine + RK4 (S-free) ----------------
// f = alph*(az - z) + z@M + x0
// mode 0 (eval1, z=znb): zout = bf16(z + c1*f);  kout = bf16(f)         [c1=dt/2]
// mode 1 (eval2, z=z1):  zout = bf16(znb + c1*f); kout = bf16(f)        [c1=dt/2]
// mode 2 (eval3, z=z2):  zout = bf16(znb + c1*f)                        [c1=dt]
// mode 3 (eval4, z=z3):  znew = znb + (z3-znb)/3 + c2*(k1 + 2*k2 + f)   [c2=dt/6]
//                        zout(=znb) = bf16(znew)
// mode 4: same as 3 but write f32 out (first 128 cols), no zout
__global__ __launch_bounds__(256, 8) void k_eval(
    const uint16_t* __restrict__ zsrc, const uint16_t* __restrict__ znb,
    uint16_t* __restrict__ zout, uint16_t* __restrict__ kout,
    const uint16_t* __restrict__ k1, const uint16_t* __restrict__ k2,
    float* __restrict__ out,
    const uint16_t* __restrict__ az, const uint16_t* __restrict__ Mpk,
    const float* __restrict__ x, const float* __restrict__ alph,
    int N, int mode, float c1, float c2)
{
    __shared__ uint16_t gs[32][264];   // z@M result, bf16  ~16.9 KB
    __shared__ float alph_s[32];

    int t = threadIdx.x;
    int r0 = blockIdx.x * 32;
    int wv = t >> 6;
    int lane = t & 63;

    if (t < 32) alph_s[t] = (r0 + t < N) ? alph[r0 + t] : 0.f;

    // P1: A fragments straight from global (block slab = 16KB, cache-resident)
    int m = lane & 15, quad = lane >> 4;
    int half = wv & 1, whichW = wv >> 1;
    int arow = half * 16 + m;
    int garow = r0 + arow;
    bool rowok = garow < N;
    short8 afr[8];
    #pragma unroll
    for (int kt = 0; kt < 8; kt++)
        afr[kt] = rowok ? *(const short8*)(zsrc + (size_t)garow * 256 + kt * 32 + quad * 8)
                        : short8{0, 0, 0, 0, 0, 0, 0, 0};

    // P2: MFMA over 8 column tiles; results to LDS in bf16
    int lrb = half * 16 + quad * 4;
    #pragma unroll
    for (int nt = 0; nt < 8; nt++) {
        int tile = whichW * 8 + nt;
        f32x4 acc = {0.f, 0.f, 0.f, 0.f};
        #pragma unroll
        for (int kt = 0; kt < 8; kt++) {
            short8 b = ((const short8*)Mpk)[(tile * 8 + kt) * 64 + lane];
            acc = __builtin_amdgcn_mfma_f32_16x16x32_bf16(afr[kt], b, acc, 0, 0, 0);
        }
        int gcol = tile * 16 + m;
        #pragma unroll
        for (int r = 0; r < 4; r++)
            gs[lrb + r][gcol] = (uint16_t)f2bf(acc[r]);
    }
    __syncthreads();

    // P3: coalesced combine + RK4 (pure float4/ushort4 streams)
    #pragma unroll
    for (int i = 0; i < 8; i++) {
        int idx = t + i * 256;
        int row = idx >> 6, c4 = idx & 63;
        int grow = r0 + row;
        if (grow >= N) continue;
        size_t b4 = (size_t)grow * 64 + c4;
        float al = alph_s[row];
        ushort4 a4 = ((const ushort4*)az)[b4];
        ushort4 z4 = ((const ushort4*)zsrc)[b4];
        ushort4 g4 = *(const ushort4*)&gs[row][c4 * 4];
        float4 x4 = make_float4(0.f, 0.f, 0.f, 0.f);
        if (c4 < 32) x4 = ((const float4*)x)[(size_t)grow * 32 + c4];
        float zv0 = bf2f(z4.x), zv1 = bf2f(z4.y), zv2 = bf2f(z4.z), zv3 = bf2f(z4.w);
        float f0 = al * (bf2f(a4.x) - zv0) + bf2f(g4.x) + x4.x;
        float f1 = al * (bf2f(a4.y) - zv1) + bf2f(g4.y) + x4.y;
        float f2 = al * (bf2f(a4.z) - zv2) + bf2f(g4.z) + x4.z;
        float f3 = al * (bf2f(a4.w) - zv3) + bf2f(g4.w) + x4.w;
        if (mode == 0) {
            ushort4 o, k;
            o.x = (uint16_t)f2bf(zv0 + c1 * f0); o.y = (uint16_t)f2bf(zv1 + c1 * f1);
            o.z = (uint16_t)f2bf(zv2 + c1 * f2); o.w = (uint16_t)f2bf(zv3 + c1 * f3);
            k.x = (uint16_t)f2bf(f0); k.y = (uint16_t)f2bf(f1);
            k.z = (uint16_t)f2bf(f2); k.w = (uint16_t)f2bf(f3);
            ((ushort4*)zout)[b4] = o;
            ((ushort4*)kout)[b4] = k;
        } else if (mode == 1) {
            ushort4 zb = ((const ushort4*)znb)[b4];
            ushort4 o, k;
            o.x = (uint16_t)f2bf(bf2f(zb.x) + c1 * f0);
            o.y = (uint16_t)f2bf(bf2f(zb.y) + c1 * f1);
            o.z = (uint16_t)f2bf(bf2f(zb.z) + c1 * f2);
            o.w = (uint16_t)f2bf(bf2f(zb.w) + c1 * f3);
            k.x = (uint16_t)f2bf(f0); k.y = (uint16_t)f2bf(f1);
            k.z = (uint16_t)f2bf(f2); k.w = (uint16_t)f2bf(f3);
            ((ushort4*)zout)[b4] = o;
            ((ushort4*)kout)[b4] = k;
        } else if (mode == 2) {
            ushort4 zb = ((const ushort4*)znb)[b4];
            ushort4 o;
            o.x = (uint16_t)f2bf(bf2f(zb.x) + c1 * f0);
            o.y = (uint16_t)f2bf(bf2f(zb.y) + c1 * f1);
            o.z = (uint16_t)f2bf(bf2f(zb.z) + c1 * f2);
            o.w = (uint16_t)f2bf(bf2f(zb.w) + c1 * f3);
            ((ushort4*)zout)[b4] = o;
        } else {
            // znew = znb + (z3-znb)/3 + c2*(k1 + 2*k2 + f)
            ushort4 zb4 = ((const ushort4*)znb)[b4];
            ushort4 k14 = ((const ushort4*)k1)[b4];
            ushort4 k24 = ((const ushort4*)k2)[b4];
            const float third = 1.f / 3.f;
            float zb0 = bf2f(zb4.x), zb1 = bf2f(zb4.y), zb2 = bf2f(zb4.z), zb3 = bf2f(zb4.w);
            float r0v = zb0 + (zv0 - zb0) * third + c2 * (bf2f(k14.x) + 2.f * bf2f(k24.x) + f0);
            float r1v = zb1 + (zv1 - zb1) * third + c2 * (bf2f(k14.y) + 2.f * bf2f(k24.y) + f1);
            float r2v = zb2 + (zv2 - zb2) * third + c2 * (bf2f(k14.z) + 2.f * bf2f(k24.z) + f2);
            float r3v = zb3 + (zv3 - zb3) * third + c2 * (bf2f(k14.w) + 2.f * bf2f(k24.w) + f3);
            if (mode == 3) {
                ushort4 o;
                o.x = (uint16_t)f2bf(r0v); o.y = (uint16_t)f2bf(r1v);
                o.z = (uint16_t)f2bf(r2v); o.w = (uint16_t)f2bf(r3v);
                ((ushort4*)zout)[b4] = o;
            } else {
                if (c4 < 32) {
                    float4 o;
                    o.x = r0v; o.y = r1v; o.z = r2v; o.w = r3v;
                    ((float4*)out)[(size_t)grow * 32 + c4] = o;
                }
            }
        }
    }
}

__global__ void k_fill(float* __restrict__ out, int n, float v) {
    int idx = blockIdx.x * blockDim.x + threadIdx.x;
    if (idx < n) out[idx] = v;
}

static inline size_t alignup(size_t v) { return (v + 255) & ~(size_t)255; }

extern "C" void kernel_launch(void* const* d_in, const int* in_sizes, int n_in,
                              void* d_out, int out_size, void* d_ws, size_t ws_size,
                              hipStream_t stream) {
    const float* x      = (const float*)d_in[0];
    const int*   erow   = (const int*)d_in[1];
    const int*   ecol   = (const int*)d_in[2];
    const float* evals  = (const float*)d_in[3];
    const float* W_ih   = (const float*)d_in[4];
    const float* W_hh   = (const float*)d_in[5];
    const float* b_ih   = (const float*)d_in[6];
    const float* b_hh   = (const float*)d_in[7];
    const float* h      = (const float*)d_in[8];
    const float* alpha0 = (const float*)d_in[9];
    const float* W      = (const float*)d_in[10];
    const float* dvec   = (const float*)d_in[11];

    int N = in_sizes[0] / DINF;
    int E = in_sizes[1];

    char* w = (char*)d_ws;
    uint16_t* znb = (uint16_t*)w; w += alignup((size_t)N * DD * 2);   //  51.2 MB
    uint16_t* zpA = (uint16_t*)w; w += alignup((size_t)N * DD * 2);   //  51.2 MB (z1, then z3)
    uint16_t* k1b = (uint16_t*)w; w += alignup((size_t)N * DD * 2);   //  51.2 MB
    uint16_t* k2b = (uint16_t*)w; w += alignup((size_t)N * DD * 2);   //  51.2 MB
    uint16_t* az = (uint16_t*)w;  w += alignup((size_t)N * DD * 2);   //  51.2 MB
    float* alpha = (float*)w;     w += alignup((size_t)N * 4);
    float* alph = (float*)w;      w += alignup((size_t)N * 4);
    uint16_t* Mpk = (uint16_t*)w; w += alignup((size_t)DD * DD * 2);
    int* counts = (int*)w;        w += alignup((size_t)(N + 1) * 4);  // reused as cursor
    int* row_ptr = (int*)w;       w += alignup((size_t)(N + 1) * 4);
    int* blksum = (int*)w;        w += alignup((size_t)1024 * 4);
    int* cols_s = (int*)w;        w += alignup((size_t)E * 4);
    float* vals_s = (float*)w;    w += alignup((size_t)E * 4);
    size_t need = (size_t)(w - (char*)d_ws);   // ~264 MB (same as before: S -> k1+k2)

    // zpB (z2, bf16) lives in d_out; dead after eval3; mode-4 final eval
    // overwrites d_out with the fp32 result.
    uint16_t* zpB = (uint16_t*)d_out;

    if (ws_size < need) {
        k_fill<<<(out_size + 255) / 256, 256, 0, stream>>>((float*)d_out, out_size, 1000.0f);
        return;
    }

    int n1 = N + 1, nb = (n1 + 1023) / 1024;
    hipMemsetAsync(counts, 0, (size_t)n1 * 4, stream);
    k_hist<<<(E + 255) / 256, 256, 0, stream>>>(erow, counts, E);
    k_scan1<<<nb, 1024, 0, stream>>>(counts, row_ptr, blksum, n1);
    k_scan2<<<1, 1024, 0, stream>>>(blksum, nb);
    k_scan3<<<(n1 + 255) / 256, 256, 0, stream>>>(blksum, row_ptr, counts, n1);
    k_scatter<<<(E + 255) / 256, 256, 0, stream>>>(erow, ecol, evals, counts, cols_s, vals_s, E);

    k_build_m<<<DD, DD, 0, stream>>>(W, dvec, Mpk);
    k_init<<<(N * 64 + 255) / 256, 256, 0, stream>>>(x, alpha0, znb, alpha, N);

    const float dt = 0.45f;  // T_END / N_STEPS
    int gs = (N + 3) / 4, ge = (N + 31) / 32;
    for (int s = 0; s < 2; s++) {
        // eval1: z = znb -> z1 (zpA), k1
        k_spmm<<<gs, 256, 0, stream>>>(znb, row_ptr, cols_s, vals_s, W_ih, W_hh,
                                       b_ih, b_hh, h, alpha, alph, az, N);
        k_eval<<<ge, 256, 0, stream>>>(znb, znb, zpA, k1b, nullptr, nullptr, nullptr,
                                       az, Mpk, x, alph, N, 0, 0.5f * dt, 0.f);
        // eval2: z = z1 (zpA) -> z2 (zpB), k2
        k_spmm<<<gs, 256, 0, stream>>>(zpA, row_ptr, cols_s, vals_s, W_ih, W_hh,
                                       b_ih, b_hh, h, alpha, alph, az, N);
        k_eval<<<ge, 256, 0, stream>>>(zpA, znb, zpB, k2b, nullptr, nullptr, nullptr,
                                       az, Mpk, x, alph, N, 1, 0.5f * dt, 0.f);
        // eval3: z = z2 (zpB) -> z3 (zpA)
        k_spmm<<<gs, 256, 0, stream>>>(zpB, row_ptr, cols_s, vals_s, W_ih, W_hh,
                                       b_ih, b_hh, h, alpha, alph, az, N);
        k_eval<<<ge, 256, 0, stream>>>(zpB, znb, zpA, nullptr, nullptr, nullptr, nullptr,
                                       az, Mpk, x, alph, N, 2, dt, 0.f);
        // eval4: z = z3 (zpA) -> znew
        k_spmm<<<gs, 256, 0, stream>>>(zpA, row_ptr, cols_s, vals_s, W_ih, W_hh,
                                       b_ih, b_hh, h, alpha, alph, az, N);
        if (s == 0) {
            k_eval<<<ge, 256, 0, stream>>>(zpA, znb, znb, nullptr, k1b, k2b, nullptr,
                                           az, Mpk, x, alph, N, 3, 0.f, dt / 6.f);
        } else {
            // final: emit fp32 output directly (first 128 cols)
            k_eval<<<ge, 256, 0, stream>>>(zpA, znb, nullptr, nullptr, k1b, k2b,
                                           (float*)d_out, az, Mpk, x, alph,
                                           N, 4, 0.f, dt / 6.f);
        }
    }
}

// Round 6
// 1491.113 us; speedup vs baseline: 1.4562x; 1.0441x over previous
//
#include <hip/hip_runtime.h>
#include <stdint.h>

#define DD 256
#define DINF 128

typedef __attribute__((ext_vector_type(8))) short short8;
typedef __attribute__((ext_vector_type(4))) float f32x4;

__device__ __forceinline__ short f2bf(float f) {
    union { float f; uint32_t u; } c{f};
    uint32_t r = (c.u + 0x7fffu + ((c.u >> 16) & 1u)) >> 16;
    return (short)(uint16_t)r;
}

__device__ __forceinline__ float bf2f(uint16_t b) {
    union { uint32_t u; float f; } c;
    c.u = ((uint32_t)b) << 16;
    return c.f;
}

// ---------------- CSR build ----------------
__global__ void k_hist(const int* __restrict__ rows, int* __restrict__ counts, int E) {
    int e = blockIdx.x * blockDim.x + threadIdx.x;
    if (e < E) atomicAdd(&counts[rows[e] + 1], 1);
}

__global__ void k_scan1(const int* __restrict__ counts, int* __restrict__ part,
                        int* __restrict__ blksum, int n1) {
    __shared__ int tmp[1024];
    int b = blockIdx.x, t = threadIdx.x, i = b * 1024 + t;
    int v = (i < n1) ? counts[i] : 0;
    tmp[t] = v;
    __syncthreads();
    for (int off = 1; off < 1024; off <<= 1) {
        int a = (t >= off) ? tmp[t - off] : 0;
        __syncthreads();
        tmp[t] += a;
        __syncthreads();
    }
    if (i < n1) part[i] = tmp[t];
    if (t == 1023) blksum[b] = tmp[t];
}

__global__ void k_scan2(int* __restrict__ blksum, int nb) {
    __shared__ int tmp[1024];
    int t = threadIdx.x;
    int v = (t < nb) ? blksum[t] : 0;
    tmp[t] = v;
    __syncthreads();
    for (int off = 1; off < 1024; off <<= 1) {
        int a = (t >= off) ? tmp[t - off] : 0;
        __syncthreads();
        tmp[t] += a;
        __syncthreads();
    }
    if (t < nb) blksum[t] = tmp[t];
}

__global__ void k_scan3(const int* __restrict__ blksum, int* __restrict__ row_ptr,
                        int* __restrict__ cursor, int n1) {
    int i = blockIdx.x * blockDim.x + threadIdx.x;
    if (i < n1) {
        int b = i >> 10;
        int off = (b > 0) ? blksum[b - 1] : 0;
        int v = row_ptr[i] + off;
        row_ptr[i] = v;
        cursor[i] = v;
    }
}

__global__ void k_scatter(const int* __restrict__ rows, const int* __restrict__ cols,
                          const float* __restrict__ vals, int* __restrict__ cursor,
                          int* __restrict__ cols_s, float* __restrict__ vals_s, int E) {
    int e = blockIdx.x * blockDim.x + threadIdx.x;
    if (e < E) {
        int r = rows[e];
        int pos = atomicAdd(&cursor[r], 1);
        cols_s[pos] = cols[e];
        vals_s[pos] = vals[e];
    }
}

// ---------------- M = (W*clip(d))@W^T - I, packed in MFMA B-fragment order ----------------
__global__ void k_build_m(const float* __restrict__ W, const float* __restrict__ dvec,
                          uint16_t* __restrict__ Mpk) {
    __shared__ float u[DD];
    int n = blockIdx.x, k = threadIdx.x;
    float dj = dvec[k];
    dj = fminf(fmaxf(dj, 0.f), 1.f);
    u[k] = W[n * DD + k] * dj;
    __syncthreads();
    float acc = 0.f;
    for (int j = 0; j < DD; j++) acc += u[j] * W[k * DD + j];
    acc -= (n == k) ? 1.f : 0.f;
    int tile = n >> 4, m = n & 15, kt = k >> 5, quad = (k >> 3) & 3, j = k & 7;
    int lane = quad * 16 + m;
    Mpk[(((tile * 8 + kt) * 64 + lane) << 3) + j] = (uint16_t)f2bf(acc);
}

// ---------------- init: znb = bf16([x,0]), xb = bf16(x), alpha = alpha0 ----------------
__global__ void k_init(const float* __restrict__ x, const float* __restrict__ alpha0,
                       uint16_t* __restrict__ znb, uint16_t* __restrict__ xb,
                       float* __restrict__ alpha, int N) {
    int idx = blockIdx.x * blockDim.x + threadIdx.x;
    int total = N * 64;
    if (idx < total) {
        int row = idx >> 6, c4 = idx & 63;
        float4 v = make_float4(0.f, 0.f, 0.f, 0.f);
        if (c4 < 32) v = ((const float4*)x)[(size_t)row * 32 + c4];
        ushort4 b;
        b.x = (uint16_t)f2bf(v.x); b.y = (uint16_t)f2bf(v.y);
        b.z = (uint16_t)f2bf(v.z); b.w = (uint16_t)f2bf(v.w);
        ((ushort4*)znb)[idx] = b;
        if (xb && c4 < 32) ((ushort4*)xb)[(size_t)row * 32 + c4] = b;
    }
    if (idx < N) alpha[idx] = alpha0[idx];
}

// ---------------- SpMM + alpha: one row per wave, chunk-of-4 gather ----------
// az = bf16(A*z); alpha update; alph = 0.5*sigmoid(alpha)
__global__ void k_spmm(const uint16_t* __restrict__ z, const int* __restrict__ row_ptr,
                       const int* __restrict__ cols_s, const float* __restrict__ vals_s,
                       const float* __restrict__ W_ih, const float* __restrict__ W_hh,
                       const float* __restrict__ b_ih, const float* __restrict__ b_hh,
                       const float* __restrict__ hbuf, float* __restrict__ alpha,
                       float* __restrict__ alph, uint16_t* __restrict__ az, int N) {
    int wave = (int)((blockIdx.x * (size_t)blockDim.x + threadIdx.x) >> 6);
    int lane = threadIdx.x & 63;
    if (wave >= N) return;

    // own-row eval point (cols 4*lane..+3)
    ushort4 zr4 = ((const ushort4*)z)[(size_t)wave * 64 + lane];
    float z0 = bf2f(zr4.x), z1 = bf2f(zr4.y), z2 = bf2f(zr4.z), z3 = bf2f(zr4.w);

    // RNNCell dot partials
    float4 w0 = ((const float4*)W_ih)[lane];
    float4 w1 = ((const float4*)(W_ih + DD))[lane];
    float s0 = z0 * w0.x + z1 * w0.y + z2 * w0.z + z3 * w0.w;
    float s1 = z0 * w1.x + z1 * w1.y + z2 * w1.z + z3 * w1.w;

    // gather in chunks of 4: 4 col/val loads then 4 independent 512B row
    // fetches in flight per chunk (branches are wave-uniform: degree is per-row)
    int s = row_ptr[wave], e = row_ptr[wave + 1];
    float4 acc = make_float4(0.f, 0.f, 0.f, 0.f);
    for (int i = s; i < e; i += 4) {
        int rem = e - i;
        int ca = cols_s[i];
        float va = vals_s[i];
        int cb = 0, cc = 0, cd = 0;
        float vb = 0.f, vc = 0.f, vd = 0.f;
        if (rem > 1) { cb = cols_s[i + 1]; vb = vals_s[i + 1]; }
        if (rem > 2) { cc = cols_s[i + 2]; vc = vals_s[i + 2]; }
        if (rem > 3) { cd = cols_s[i + 3]; vd = vals_s[i + 3]; }
        ushort4 ra = ((const ushort4*)z)[(size_t)ca * 64 + lane];
        ushort4 rb = (rem > 1) ? ((const ushort4*)z)[(size_t)cb * 64 + lane]
                               : make_ushort4(0, 0, 0, 0);
        ushort4 rc = (rem > 2) ? ((const ushort4*)z)[(size_t)cc * 64 + lane]
                               : make_ushort4(0, 0, 0, 0);
        ushort4 rd = (rem > 3) ? ((const ushort4*)z)[(size_t)cd * 64 + lane]
                               : make_ushort4(0, 0, 0, 0);
        acc.x += va * bf2f(ra.x) + vb * bf2f(rb.x) + vc * bf2f(rc.x) + vd * bf2f(rd.x);
        acc.y += va * bf2f(ra.y) + vb * bf2f(rb.y) + vc * bf2f(rc.y) + vd * bf2f(rd.y);
        acc.z += va * bf2f(ra.z) + vb * bf2f(rb.z) + vc * bf2f(rc.z) + vd * bf2f(rd.z);
        acc.w += va * bf2f(ra.w) + vb * bf2f(rb.w) + vc * bf2f(rc.w) + vd * bf2f(rd.w);
    }
    ushort4 o;
    o.x = (uint16_t)f2bf(acc.x); o.y = (uint16_t)f2bf(acc.y);
    o.z = (uint16_t)f2bf(acc.z); o.w = (uint16_t)f2bf(acc.w);
    ((ushort4*)az)[(size_t)wave * 64 + lane] = o;

    // wave-reduce the dots, lane 0 does the alpha update
    #pragma unroll
    for (int off = 32; off >= 1; off >>= 1) {
        s0 += __shfl_down(s0, off, 64);
        s1 += __shfl_down(s1, off, 64);
    }
    if (lane == 0) {
        float h0 = hbuf[wave * 2], h1 = hbuf[wave * 2 + 1];
        float cc0 = b_ih[0] + b_hh[0] + h0 * W_hh[0] + h1 * W_hh[1];
        float cc1 = b_ih[1] + b_hh[1] + h0 * W_hh[2] + h1 * W_hh[3];
        float anew = alpha[wave] * tanhf(s0 + cc0) + tanhf(s1 + cc1);
        alpha[wave] = anew;
        alph[wave] = 0.5f / (1.f + expf(-anew));
    }
}

// ---------------- eval: z@M (MFMA) + combine + RK4 (k-free, z-sum form) --------
// f = alph*(az - z) + z@M + x0
// mode 0 (eval1, z=znb): zout = bf16(z + c1*f)                       [c1=dt/2]
// mode 1 (eval2/3):      zout = bf16(znb + c1*f)                     [c1=dt/2, dt]
// mode 3 (eval4, z=z3):  znew = znb + (z1 + 2*z2 + z3 - 4*znb)/3 + c2*f   [c2=dt/6]
//                        zout(=znb) = bf16(znew)
// mode 4: same as 3 but write f32 out (first 128 cols), no zout
__global__ __launch_bounds__(256, 8) void k_eval(
    const uint16_t* __restrict__ zsrc, const uint16_t* __restrict__ znb,
    uint16_t* __restrict__ zout,
    const uint16_t* __restrict__ z1b, const uint16_t* __restrict__ z2b,
    float* __restrict__ out,
    const uint16_t* __restrict__ az, const uint16_t* __restrict__ Mpk,
    const float* __restrict__ x, const uint16_t* __restrict__ xb,
    const float* __restrict__ alph,
    int N, int mode, float c1, float c2)
{
    __shared__ uint16_t gs[32][264];   // z@M result, bf16  ~16.9 KB
    __shared__ float alph_s[32];

    int t = threadIdx.x;
    int r0 = blockIdx.x * 32;
    int wv = t >> 6;
    int lane = t & 63;

    if (t < 32) alph_s[t] = (r0 + t < N) ? alph[r0 + t] : 0.f;

    // P1: A fragments straight from global (block slab = 16KB, cache-resident)
    int m = lane & 15, quad = lane >> 4;
    int half = wv & 1, whichW = wv >> 1;
    int arow = half * 16 + m;
    int garow = r0 + arow;
    bool rowok = garow < N;
    short8 afr[8];
    #pragma unroll
    for (int kt = 0; kt < 8; kt++)
        afr[kt] = rowok ? *(const short8*)(zsrc + (size_t)garow * 256 + kt * 32 + quad * 8)
                        : short8{0, 0, 0, 0, 0, 0, 0, 0};

    // P2: MFMA over 8 column tiles; results to LDS in bf16
    int lrb = half * 16 + quad * 4;
    #pragma unroll
    for (int nt = 0; nt < 8; nt++) {
        int tile = whichW * 8 + nt;
        f32x4 acc = {0.f, 0.f, 0.f, 0.f};
        #pragma unroll
        for (int kt = 0; kt < 8; kt++) {
            short8 b = ((const short8*)Mpk)[(tile * 8 + kt) * 64 + lane];
            acc = __builtin_amdgcn_mfma_f32_16x16x32_bf16(afr[kt], b, acc, 0, 0, 0);
        }
        int gcol = tile * 16 + m;
        #pragma unroll
        for (int r = 0; r < 4; r++)
            gs[lrb + r][gcol] = (uint16_t)f2bf(acc[r]);
    }
    __syncthreads();

    // P3: coalesced combine + RK4 (pure float4/ushort4 streams)
    #pragma unroll
    for (int i = 0; i < 8; i++) {
        int idx = t + i * 256;
        int row = idx >> 6, c4 = idx & 63;
        int grow = r0 + row;
        if (grow >= N) continue;
        size_t b4 = (size_t)grow * 64 + c4;
        float al = alph_s[row];
        ushort4 a4 = ((const ushort4*)az)[b4];
        ushort4 z4 = ((const ushort4*)zsrc)[b4];
        ushort4 g4 = *(const ushort4*)&gs[row][c4 * 4];
        float4 x4 = make_float4(0.f, 0.f, 0.f, 0.f);
        if (c4 < 32) {
            if (xb) {
                ushort4 xb4 = ((const ushort4*)xb)[(size_t)grow * 32 + c4];
                x4.x = bf2f(xb4.x); x4.y = bf2f(xb4.y);
                x4.z = bf2f(xb4.z); x4.w = bf2f(xb4.w);
            } else {
                x4 = ((const float4*)x)[(size_t)grow * 32 + c4];
            }
        }
        float zv0 = bf2f(z4.x), zv1 = bf2f(z4.y), zv2 = bf2f(z4.z), zv3 = bf2f(z4.w);
        float f0 = al * (bf2f(a4.x) - zv0) + bf2f(g4.x) + x4.x;
        float f1 = al * (bf2f(a4.y) - zv1) + bf2f(g4.y) + x4.y;
        float f2 = al * (bf2f(a4.z) - zv2) + bf2f(g4.z) + x4.z;
        float f3 = al * (bf2f(a4.w) - zv3) + bf2f(g4.w) + x4.w;
        if (mode == 0) {
            ushort4 o;
            o.x = (uint16_t)f2bf(zv0 + c1 * f0); o.y = (uint16_t)f2bf(zv1 + c1 * f1);
            o.z = (uint16_t)f2bf(zv2 + c1 * f2); o.w = (uint16_t)f2bf(zv3 + c1 * f3);
            ((ushort4*)zout)[b4] = o;
        } else if (mode == 1) {
            ushort4 zb = ((const ushort4*)znb)[b4];
            ushort4 o;
            o.x = (uint16_t)f2bf(bf2f(zb.x) + c1 * f0);
            o.y = (uint16_t)f2bf(bf2f(zb.y) + c1 * f1);
            o.z = (uint16_t)f2bf(bf2f(zb.z) + c1 * f2);
            o.w = (uint16_t)f2bf(bf2f(zb.w) + c1 * f3);
            ((ushort4*)zout)[b4] = o;
        } else {
            // znew = znb + (z1 + 2*z2 + z3 - 4*znb)/3 + c2*f   (z3 = zv)
            ushort4 zb4 = ((const ushort4*)znb)[b4];
            ushort4 z14 = ((const ushort4*)z1b)[b4];
            ushort4 z24 = ((const ushort4*)z2b)[b4];
            const float third = 1.f / 3.f;
            float zb0 = bf2f(zb4.x), zb1 = bf2f(zb4.y), zb2 = bf2f(zb4.z), zb3 = bf2f(zb4.w);
            float r0v = zb0 + (bf2f(z14.x) + 2.f * bf2f(z24.x) + zv0 - 4.f * zb0) * third + c2 * f0;
            float r1v = zb1 + (bf2f(z14.y) + 2.f * bf2f(z24.y) + zv1 - 4.f * zb1) * third + c2 * f1;
            float r2v = zb2 + (bf2f(z14.z) + 2.f * bf2f(z24.z) + zv2 - 4.f * zb2) * third + c2 * f2;
            float r3v = zb3 + (bf2f(z14.w) + 2.f * bf2f(z24.w) + zv3 - 4.f * zb3) * third + c2 * f3;
            if (mode == 3) {
                ushort4 o;
                o.x = (uint16_t)f2bf(r0v); o.y = (uint16_t)f2bf(r1v);
                o.z = (uint16_t)f2bf(r2v); o.w = (uint16_t)f2bf(r3v);
                ((ushort4*)zout)[b4] = o;
            } else {
                if (c4 < 32) {
                    float4 o;
                    o.x = r0v; o.y = r1v; o.z = r2v; o.w = r3v;
                    ((float4*)out)[(size_t)grow * 32 + c4] = o;
                }
            }
        }
    }
}

__global__ void k_fill(float* __restrict__ out, int n, float v) {
    int idx = blockIdx.x * blockDim.x + threadIdx.x;
    if (idx < n) out[idx] = v;
}

static inline size_t alignup(size_t v) { return (v + 255) & ~(size_t)255; }

extern "C" void kernel_launch(void* const* d_in, const int* in_sizes, int n_in,
                              void* d_out, int out_size, void* d_ws, size_t ws_size,
                              hipStream_t stream) {
    const float* x      = (const float*)d_in[0];
    const int*   erow   = (const int*)d_in[1];
    const int*   ecol   = (const int*)d_in[2];
    const float* evals  = (const float*)d_in[3];
    const float* W_ih   = (const float*)d_in[4];
    const float* W_hh   = (const float*)d_in[5];
    const float* b_ih   = (const float*)d_in[6];
    const float* b_hh   = (const float*)d_in[7];
    const float* h      = (const float*)d_in[8];
    const float* alpha0 = (const float*)d_in[9];
    const float* W      = (const float*)d_in[10];
    const float* dvec   = (const float*)d_in[11];

    int N = in_sizes[0] / DINF;
    int E = in_sizes[1];

    char* w = (char*)d_ws;
    uint16_t* znb = (uint16_t*)w; w += alignup((size_t)N * DD * 2);   //  51.2 MB
    uint16_t* z1b = (uint16_t*)w; w += alignup((size_t)N * DD * 2);   //  51.2 MB
    uint16_t* z2b = (uint16_t*)w; w += alignup((size_t)N * DD * 2);   //  51.2 MB
    uint16_t* z3b = (uint16_t*)w; w += alignup((size_t)N * DD * 2);   //  51.2 MB
    uint16_t* az = (uint16_t*)w;  w += alignup((size_t)N * DD * 2);   //  51.2 MB
    float* alpha = (float*)w;     w += alignup((size_t)N * 4);
    float* alph = (float*)w;      w += alignup((size_t)N * 4);
    uint16_t* Mpk = (uint16_t*)w; w += alignup((size_t)DD * DD * 2);
    int* counts = (int*)w;        w += alignup((size_t)(N + 1) * 4);  // reused as cursor
    int* row_ptr = (int*)w;       w += alignup((size_t)(N + 1) * 4);
    int* blksum = (int*)w;        w += alignup((size_t)1024 * 4);
    int* cols_s = (int*)w;        w += alignup((size_t)E * 4);
    float* vals_s = (float*)w;    w += alignup((size_t)E * 4);
    size_t need_min = (size_t)(w - (char*)d_ws);   // ~264 MB
    uint16_t* xb = (uint16_t*)w;  // optional bf16 x copy, +25.6 MB
    size_t need_full = need_min + alignup((size_t)N * DINF * 2);

    if (ws_size < need_min) {
        k_fill<<<(out_size + 255) / 256, 256, 0, stream>>>((float*)d_out, out_size, 1000.0f);
        return;
    }
    if (ws_size < need_full) xb = nullptr;   // graceful fallback to f32 x reads

    int n1 = N + 1, nb = (n1 + 1023) / 1024;
    hipMemsetAsync(counts, 0, (size_t)n1 * 4, stream);
    k_hist<<<(E + 255) / 256, 256, 0, stream>>>(erow, counts, E);
    k_scan1<<<nb, 1024, 0, stream>>>(counts, row_ptr, blksum, n1);
    k_scan2<<<1, 1024, 0, stream>>>(blksum, nb);
    k_scan3<<<(n1 + 255) / 256, 256, 0, stream>>>(blksum, row_ptr, counts, n1);
    k_scatter<<<(E + 255) / 256, 256, 0, stream>>>(erow, ecol, evals, counts, cols_s, vals_s, E);

    k_build_m<<<DD, DD, 0, stream>>>(W, dvec, Mpk);
    k_init<<<(N * 64 + 255) / 256, 256, 0, stream>>>(x, alpha0, znb, xb, alpha, N);

    const float dt = 0.45f;  // T_END / N_STEPS
    int gs = (N + 3) / 4, ge = (N + 31) / 32;
    for (int s = 0; s < 2; s++) {
        // eval1: z = znb -> z1
        k_spmm<<<gs, 256, 0, stream>>>(znb, row_ptr, cols_s, vals_s, W_ih, W_hh,
                                       b_ih, b_hh, h, alpha, alph, az, N);
        k_eval<<<ge, 256, 0, stream>>>(znb, znb, z1b, nullptr, nullptr, nullptr,
                                       az, Mpk, x, xb, alph, N, 0, 0.5f * dt, 0.f);
        // eval2: z = z1 -> z2
        k_spmm<<<gs, 256, 0, stream>>>(z1b, row_ptr, cols_s, vals_s, W_ih, W_hh,
                                       b_ih, b_hh, h, alpha, alph, az, N);
        k_eval<<<ge, 256, 0, stream>>>(z1b, znb, z2b, nullptr, nullptr, nullptr,
                                       az, Mpk, x, xb, alph, N, 1, 0.5f * dt, 0.f);
        // eval3: z = z2 -> z3
        k_spmm<<<gs, 256, 0, stream>>>(z2b, row_ptr, cols_s, vals_s, W_ih, W_hh,
                                       b_ih, b_hh, h, alpha, alph, az, N);
        k_eval<<<ge, 256, 0, stream>>>(z2b, znb, z3b, nullptr, nullptr, nullptr,
                                       az, Mpk, x, xb, alph, N, 1, dt, 0.f);
        // eval4: z = z3 -> znew = znb + (z1+2z2+z3-4znb)/3 + dt/6*f4
        k_spmm<<<gs, 256, 0, stream>>>(z3b, row_ptr, cols_s, vals_s, W_ih, W_hh,
                                       b_ih, b_hh, h, alpha, alph, az, N);
        if (s == 0) {
            k_eval<<<ge, 256, 0, stream>>>(z3b, znb, znb, z1b, z2b, nullptr,
                                           az, Mpk, x, xb, alph, N, 3, 0.f, dt / 6.f);
        } else {
            // final: emit fp32 output directly (first 128 cols)
            k_eval<<<ge, 256, 0, stream>>>(z3b, znb, nullptr, z1b, z2b,
                                           (float*)d_out, az, Mpk, x, xb, alph,
                                           N, 4, 0.f, dt / 6.f);
        }
    }
}

// Round 7
// 1441.912 us; speedup vs baseline: 1.5059x; 1.0341x over previous
//
#include <hip/hip_runtime.h>
#include <stdint.h>

#define DD 256
#define DINF 128

typedef __attribute__((ext_vector_type(8))) short short8;
typedef __attribute__((ext_vector_type(4))) float f32x4;

__device__ __forceinline__ short f2bf(float f) {
    union { float f; uint32_t u; } c{f};
    uint32_t r = (c.u + 0x7fffu + ((c.u >> 16) & 1u)) >> 16;
    return (short)(uint16_t)r;
}

__device__ __forceinline__ float bf2f(uint16_t b) {
    union { uint32_t u; float f; } c;
    c.u = ((uint32_t)b) << 16;
    return c.f;
}

// ---------------- CSR build ----------------
__global__ void k_hist(const int* __restrict__ rows, int* __restrict__ counts, int E) {
    int e = blockIdx.x * blockDim.x + threadIdx.x;
    if (e < E) atomicAdd(&counts[rows[e] + 1], 1);
}

__global__ void k_scan1(const int* __restrict__ counts, int* __restrict__ part,
                        int* __restrict__ blksum, int n1) {
    __shared__ int tmp[1024];
    int b = blockIdx.x, t = threadIdx.x, i = b * 1024 + t;
    int v = (i < n1) ? counts[i] : 0;
    tmp[t] = v;
    __syncthreads();
    for (int off = 1; off < 1024; off <<= 1) {
        int a = (t >= off) ? tmp[t - off] : 0;
        __syncthreads();
        tmp[t] += a;
        __syncthreads();
    }
    if (i < n1) part[i] = tmp[t];
    if (t == 1023) blksum[b] = tmp[t];
}

__global__ void k_scan2(int* __restrict__ blksum, int nb) {
    __shared__ int tmp[1024];
    int t = threadIdx.x;
    int v = (t < nb) ? blksum[t] : 0;
    tmp[t] = v;
    __syncthreads();
    for (int off = 1; off < 1024; off <<= 1) {
        int a = (t >= off) ? tmp[t - off] : 0;
        __syncthreads();
        tmp[t] += a;
        __syncthreads();
    }
    if (t < nb) blksum[t] = tmp[t];
}

__global__ void k_scan3(const int* __restrict__ blksum, int* __restrict__ row_ptr,
                        int* __restrict__ cursor, int n1) {
    int i = blockIdx.x * blockDim.x + threadIdx.x;
    if (i < n1) {
        int b = i >> 10;
        int off = (b > 0) ? blksum[b - 1] : 0;
        int v = row_ptr[i] + off;
        row_ptr[i] = v;
        cursor[i] = v;
    }
}

__global__ void k_scatter(const int* __restrict__ rows, const int* __restrict__ cols,
                          const float* __restrict__ vals, int* __restrict__ cursor,
                          int* __restrict__ cols_s, float* __restrict__ vals_s, int E) {
    int e = blockIdx.x * blockDim.x + threadIdx.x;
    if (e < E) {
        int r = rows[e];
        int pos = atomicAdd(&cursor[r], 1);
        cols_s[pos] = cols[e];
        vals_s[pos] = vals[e];
    }
}

// ---------------- M = (W*clip(d))@W^T - I, packed in MFMA B-fragment order ----------------
__global__ void k_build_m(const float* __restrict__ W, const float* __restrict__ dvec,
                          uint16_t* __restrict__ Mpk) {
    __shared__ float u[DD];
    int n = blockIdx.x, k = threadIdx.x;
    float dj = dvec[k];
    dj = fminf(fmaxf(dj, 0.f), 1.f);
    u[k] = W[n * DD + k] * dj;
    __syncthreads();
    float acc = 0.f;
    for (int j = 0; j < DD; j++) acc += u[j] * W[k * DD + j];
    acc -= (n == k) ? 1.f : 0.f;
    int tile = n >> 4, m = n & 15, kt = k >> 5, quad = (k >> 3) & 3, j = k & 7;
    int lane = quad * 16 + m;
    Mpk[(((tile * 8 + kt) * 64 + lane) << 3) + j] = (uint16_t)f2bf(acc);
}

// ---------------- init: znb = bf16([x,0]), xb = bf16(x), alpha = alpha0 ----------------
__global__ void k_init(const float* __restrict__ x, const float* __restrict__ alpha0,
                       uint16_t* __restrict__ znb, uint16_t* __restrict__ xb,
                       float* __restrict__ alpha, int N) {
    int idx = blockIdx.x * blockDim.x + threadIdx.x;
    int total = N * 64;
    if (idx < total) {
        int row = idx >> 6, c4 = idx & 63;
        float4 v = make_float4(0.f, 0.f, 0.f, 0.f);
        if (c4 < 32) v = ((const float4*)x)[(size_t)row * 32 + c4];
        ushort4 b;
        b.x = (uint16_t)f2bf(v.x); b.y = (uint16_t)f2bf(v.y);
        b.z = (uint16_t)f2bf(v.z); b.w = (uint16_t)f2bf(v.w);
        ((ushort4*)znb)[idx] = b;
        if (c4 < 32) ((ushort4*)xb)[(size_t)row * 32 + c4] = b;
    }
    if (idx < N) alpha[idx] = alpha0[idx];
}

// ---------------- SpMM + alpha: one row per wave, chunk-of-4 gather ----------
// az = bf16(A*z); alpha update; alph = 0.5*sigmoid(alpha)
__global__ void k_spmm(const uint16_t* __restrict__ z, const int* __restrict__ row_ptr,
                       const int* __restrict__ cols_s, const float* __restrict__ vals_s,
                       const float* __restrict__ W_ih, const float* __restrict__ W_hh,
                       const float* __restrict__ b_ih, const float* __restrict__ b_hh,
                       const float* __restrict__ hbuf, float* __restrict__ alpha,
                       float* __restrict__ alph, uint16_t* __restrict__ az, int N) {
    int wave = (int)((blockIdx.x * (size_t)blockDim.x + threadIdx.x) >> 6);
    int lane = threadIdx.x & 63;
    if (wave >= N) return;

    // own-row eval point (cols 4*lane..+3)
    ushort4 zr4 = ((const ushort4*)z)[(size_t)wave * 64 + lane];
    float z0 = bf2f(zr4.x), z1 = bf2f(zr4.y), z2 = bf2f(zr4.z), z3 = bf2f(zr4.w);

    // RNNCell dot partials
    float4 w0 = ((const float4*)W_ih)[lane];
    float4 w1 = ((const float4*)(W_ih + DD))[lane];
    float s0 = z0 * w0.x + z1 * w0.y + z2 * w0.z + z3 * w0.w;
    float s1 = z0 * w1.x + z1 * w1.y + z2 * w1.z + z3 * w1.w;

    // gather in chunks of 4: 4 col/val loads then 4 independent 512B row
    // fetches in flight per chunk (branches are wave-uniform: degree is per-row)
    int s = row_ptr[wave], e = row_ptr[wave + 1];
    float4 acc = make_float4(0.f, 0.f, 0.f, 0.f);
    for (int i = s; i < e; i += 4) {
        int rem = e - i;
        int ca = cols_s[i];
        float va = vals_s[i];
        int cb = 0, cc = 0, cd = 0;
        float vb = 0.f, vc = 0.f, vd = 0.f;
        if (rem > 1) { cb = cols_s[i + 1]; vb = vals_s[i + 1]; }
        if (rem > 2) { cc = cols_s[i + 2]; vc = vals_s[i + 2]; }
        if (rem > 3) { cd = cols_s[i + 3]; vd = vals_s[i + 3]; }
        ushort4 ra = ((const ushort4*)z)[(size_t)ca * 64 + lane];
        ushort4 rb = (rem > 1) ? ((const ushort4*)z)[(size_t)cb * 64 + lane]
                               : make_ushort4(0, 0, 0, 0);
        ushort4 rc = (rem > 2) ? ((const ushort4*)z)[(size_t)cc * 64 + lane]
                               : make_ushort4(0, 0, 0, 0);
        ushort4 rd = (rem > 3) ? ((const ushort4*)z)[(size_t)cd * 64 + lane]
                               : make_ushort4(0, 0, 0, 0);
        acc.x += va * bf2f(ra.x) + vb * bf2f(rb.x) + vc * bf2f(rc.x) + vd * bf2f(rd.x);
        acc.y += va * bf2f(ra.y) + vb * bf2f(rb.y) + vc * bf2f(rc.y) + vd * bf2f(rd.y);
        acc.z += va * bf2f(ra.z) + vb * bf2f(rb.z) + vc * bf2f(rc.z) + vd * bf2f(rd.z);
        acc.w += va * bf2f(ra.w) + vb * bf2f(rb.w) + vc * bf2f(rc.w) + vd * bf2f(rd.w);
    }
    ushort4 o;
    o.x = (uint16_t)f2bf(acc.x); o.y = (uint16_t)f2bf(acc.y);
    o.z = (uint16_t)f2bf(acc.z); o.w = (uint16_t)f2bf(acc.w);
    ((ushort4*)az)[(size_t)wave * 64 + lane] = o;

    // wave-reduce the dots, lane 0 does the alpha update
    #pragma unroll
    for (int off = 32; off >= 1; off >>= 1) {
        s0 += __shfl_down(s0, off, 64);
        s1 += __shfl_down(s1, off, 64);
    }
    if (lane == 0) {
        float h0 = hbuf[wave * 2], h1 = hbuf[wave * 2 + 1];
        float cc0 = b_ih[0] + b_hh[0] + h0 * W_hh[0] + h1 * W_hh[1];
        float cc1 = b_ih[1] + b_hh[1] + h0 * W_hh[2] + h1 * W_hh[3];
        float anew = alpha[wave] * tanhf(s0 + cc0) + tanhf(s1 + cc1);
        alpha[wave] = anew;
        alph[wave] = 0.5f / (1.f + expf(-anew));
    }
}

// ---------------- eval: z@M (MFMA) + combine + RK4 (in-place, D-fold) ----------
// f = alph*(az - z) + z@M + x0
// All z-buffers may alias (in-place): every global read of a row is done either
// by the owning thread at the address it later writes (P3, read-before-write in
// program order) or pre-barrier (P1 frag loads; __syncthreads drains vmcnt
// before any P3 store issues). zsrc/znb/zout are NOT restrict for this reason.
// mode 0 (eval1, zsrc=znb): zout(B1) = bf16(z + c1*f)              [c1=dt/2]
// mode 1 (eval2, zsrc=z1):  z2f = znb + c1*f; zout(B1,in-place) = bf16(z2f);
//                           Pout = bf16(z1 + 2*z2f - 3*znb)        [c1=dt/2]
// mode 2 (eval3, zsrc=z2):  zout(B1,in-place) = bf16(znb + c1*f)   [c1=dt]
// mode 3 (eval4, zsrc=z3):  znew = znb + (D + z3 - znb)/3 + c2*f   [c2=dt/6]
//                           zout(=znb,in-place) = bf16(znew)
// mode 4: same as 3 but write f32 out (first 128 cols), no zout
__global__ __launch_bounds__(256, 8) void k_eval(
    const uint16_t* zsrc, const uint16_t* znb, uint16_t* zout,
    uint16_t* __restrict__ Pout, const uint16_t* __restrict__ Pin,
    float* __restrict__ out,
    const uint16_t* __restrict__ az, const uint16_t* __restrict__ Mpk,
    const uint16_t* __restrict__ xb, const float* __restrict__ alph,
    int N, int mode, float c1, float c2)
{
    __shared__ uint16_t gs[32][264];   // z@M result, bf16  ~16.9 KB
    __shared__ float alph_s[32];

    int t = threadIdx.x;
    int r0 = blockIdx.x * 32;
    int wv = t >> 6;
    int lane = t & 63;

    if (t < 32) alph_s[t] = (r0 + t < N) ? alph[r0 + t] : 0.f;

    // P1: A fragments straight from global (block slab = 16KB, cache-resident)
    int m = lane & 15, quad = lane >> 4;
    int half = wv & 1, whichW = wv >> 1;
    int arow = half * 16 + m;
    int garow = r0 + arow;
    bool rowok = garow < N;
    short8 afr[8];
    #pragma unroll
    for (int kt = 0; kt < 8; kt++)
        afr[kt] = rowok ? *(const short8*)(zsrc + (size_t)garow * 256 + kt * 32 + quad * 8)
                        : short8{0, 0, 0, 0, 0, 0, 0, 0};

    // P2: MFMA over 8 column tiles; results to LDS in bf16
    int lrb = half * 16 + quad * 4;
    #pragma unroll
    for (int nt = 0; nt < 8; nt++) {
        int tile = whichW * 8 + nt;
        f32x4 acc = {0.f, 0.f, 0.f, 0.f};
        #pragma unroll
        for (int kt = 0; kt < 8; kt++) {
            short8 b = ((const short8*)Mpk)[(tile * 8 + kt) * 64 + lane];
            acc = __builtin_amdgcn_mfma_f32_16x16x32_bf16(afr[kt], b, acc, 0, 0, 0);
        }
        int gcol = tile * 16 + m;
        #pragma unroll
        for (int r = 0; r < 4; r++)
            gs[lrb + r][gcol] = (uint16_t)f2bf(acc[r]);
    }
    __syncthreads();   // also drains all P1 vmem reads before any P3 store

    // P3: coalesced combine + RK4 (pure float4/ushort4 streams)
    #pragma unroll
    for (int i = 0; i < 8; i++) {
        int idx = t + i * 256;
        int row = idx >> 6, c4 = idx & 63;
        int grow = r0 + row;
        if (grow >= N) continue;
        size_t b4 = (size_t)grow * 64 + c4;
        float al = alph_s[row];
        ushort4 a4 = ((const ushort4*)az)[b4];
        ushort4 z4 = ((const ushort4*)zsrc)[b4];
        ushort4 g4 = *(const ushort4*)&gs[row][c4 * 4];
        float4 x4 = make_float4(0.f, 0.f, 0.f, 0.f);
        if (c4 < 32) {
            ushort4 xb4 = ((const ushort4*)xb)[(size_t)grow * 32 + c4];
            x4.x = bf2f(xb4.x); x4.y = bf2f(xb4.y);
            x4.z = bf2f(xb4.z); x4.w = bf2f(xb4.w);
        }
        float zv0 = bf2f(z4.x), zv1 = bf2f(z4.y), zv2 = bf2f(z4.z), zv3 = bf2f(z4.w);
        float f0 = al * (bf2f(a4.x) - zv0) + bf2f(g4.x) + x4.x;
        float f1 = al * (bf2f(a4.y) - zv1) + bf2f(g4.y) + x4.y;
        float f2 = al * (bf2f(a4.z) - zv2) + bf2f(g4.z) + x4.z;
        float f3 = al * (bf2f(a4.w) - zv3) + bf2f(g4.w) + x4.w;
        if (mode == 0) {
            ushort4 o;
            o.x = (uint16_t)f2bf(zv0 + c1 * f0); o.y = (uint16_t)f2bf(zv1 + c1 * f1);
            o.z = (uint16_t)f2bf(zv2 + c1 * f2); o.w = (uint16_t)f2bf(zv3 + c1 * f3);
            ((ushort4*)zout)[b4] = o;
        } else if (mode == 1) {
            ushort4 zb = ((const ushort4*)znb)[b4];
            float zb0 = bf2f(zb.x), zb1 = bf2f(zb.y), zb2 = bf2f(zb.z), zb3 = bf2f(zb.w);
            float z20 = zb0 + c1 * f0, z21 = zb1 + c1 * f1;
            float z22 = zb2 + c1 * f2, z23 = zb3 + c1 * f3;
            ushort4 o, p;
            o.x = (uint16_t)f2bf(z20); o.y = (uint16_t)f2bf(z21);
            o.z = (uint16_t)f2bf(z22); o.w = (uint16_t)f2bf(z23);
            p.x = (uint16_t)f2bf(zv0 + 2.f * z20 - 3.f * zb0);
            p.y = (uint16_t)f2bf(zv1 + 2.f * z21 - 3.f * zb1);
            p.z = (uint16_t)f2bf(zv2 + 2.f * z22 - 3.f * zb2);
            p.w = (uint16_t)f2bf(zv3 + 2.f * z23 - 3.f * zb3);
            ((ushort4*)zout)[b4] = o;
            ((ushort4*)Pout)[b4] = p;
        } else if (mode == 2) {
            ushort4 zb = ((const ushort4*)znb)[b4];
            ushort4 o;
            o.x = (uint16_t)f2bf(bf2f(zb.x) + c1 * f0);
            o.y = (uint16_t)f2bf(bf2f(zb.y) + c1 * f1);
            o.z = (uint16_t)f2bf(bf2f(zb.z) + c1 * f2);
            o.w = (uint16_t)f2bf(bf2f(zb.w) + c1 * f3);
            ((ushort4*)zout)[b4] = o;
        } else {
            // znew = znb + (D + z3 - znb)/3 + c2*f   (z3 = zv, D = Pin)
            ushort4 zb4 = ((const ushort4*)znb)[b4];
            ushort4 p4 = ((const ushort4*)Pin)[b4];
            const float third = 1.f / 3.f;
            float zb0 = bf2f(zb4.x), zb1 = bf2f(zb4.y), zb2 = bf2f(zb4.z), zb3 = bf2f(zb4.w);
            float r0v = zb0 + (bf2f(p4.x) + zv0 - zb0) * third + c2 * f0;
            float r1v = zb1 + (bf2f(p4.y) + zv1 - zb1) * third + c2 * f1;
            float r2v = zb2 + (bf2f(p4.z) + zv2 - zb2) * third + c2 * f2;
            float r3v = zb3 + (bf2f(p4.w) + zv3 - zb3) * third + c2 * f3;
            if (mode == 3) {
                ushort4 o;
                o.x = (uint16_t)f2bf(r0v); o.y = (uint16_t)f2bf(r1v);
                o.z = (uint16_t)f2bf(r2v); o.w = (uint16_t)f2bf(r3v);
                ((ushort4*)zout)[b4] = o;
            } else {
                if (c4 < 32) {
                    float4 o;
                    o.x = r0v; o.y = r1v; o.z = r2v; o.w = r3v;
                    ((float4*)out)[(size_t)grow * 32 + c4] = o;
                }
            }
        }
    }
}

__global__ void k_fill(float* __restrict__ out, int n, float v) {
    int idx = blockIdx.x * blockDim.x + threadIdx.x;
    if (idx < n) out[idx] = v;
}

static inline size_t alignup(size_t v) { return (v + 255) & ~(size_t)255; }

extern "C" void kernel_launch(void* const* d_in, const int* in_sizes, int n_in,
                              void* d_out, int out_size, void* d_ws, size_t ws_size,
                              hipStream_t stream) {
    const float* x      = (const float*)d_in[0];
    const int*   erow   = (const int*)d_in[1];
    const int*   ecol   = (const int*)d_in[2];
    const float* evals  = (const float*)d_in[3];
    const float* W_ih   = (const float*)d_in[4];
    const float* W_hh   = (const float*)d_in[5];
    const float* b_ih   = (const float*)d_in[6];
    const float* b_hh   = (const float*)d_in[7];
    const float* h      = (const float*)d_in[8];
    const float* alpha0 = (const float*)d_in[9];
    const float* W      = (const float*)d_in[10];
    const float* dvec   = (const float*)d_in[11];

    int N = in_sizes[0] / DINF;
    int E = in_sizes[1];

    char* w = (char*)d_ws;
    uint16_t* znb = (uint16_t*)w; w += alignup((size_t)N * DD * 2);   //  51.2 MB
    uint16_t* B1  = (uint16_t*)w; w += alignup((size_t)N * DD * 2);   //  51.2 MB (z1 -> z2 -> z3)
    uint16_t* P   = (uint16_t*)w; w += alignup((size_t)N * DD * 2);   //  51.2 MB (D-fold)
    uint16_t* az  = (uint16_t*)w; w += alignup((size_t)N * DD * 2);   //  51.2 MB
    uint16_t* xb  = (uint16_t*)w; w += alignup((size_t)N * DINF * 2); //  25.6 MB
    float* alpha = (float*)w;     w += alignup((size_t)N * 4);
    float* alph = (float*)w;      w += alignup((size_t)N * 4);
    uint16_t* Mpk = (uint16_t*)w; w += alignup((size_t)DD * DD * 2);
    int* counts = (int*)w;        w += alignup((size_t)(N + 1) * 4);  // reused as cursor
    int* row_ptr = (int*)w;       w += alignup((size_t)(N + 1) * 4);
    int* blksum = (int*)w;        w += alignup((size_t)1024 * 4);
    int* cols_s = (int*)w;        w += alignup((size_t)E * 4);
    float* vals_s = (float*)w;    w += alignup((size_t)E * 4);
    size_t need = (size_t)(w - (char*)d_ws);   // ~238 MB — whole hot set fits 256MiB L3

    if (ws_size < need) {
        k_fill<<<(out_size + 255) / 256, 256, 0, stream>>>((float*)d_out, out_size, 1000.0f);
        return;
    }

    int n1 = N + 1, nb = (n1 + 1023) / 1024;
    hipMemsetAsync(counts, 0, (size_t)n1 * 4, stream);
    k_hist<<<(E + 255) / 256, 256, 0, stream>>>(erow, counts, E);
    k_scan1<<<nb, 1024, 0, stream>>>(counts, row_ptr, blksum, n1);
    k_scan2<<<1, 1024, 0, stream>>>(blksum, nb);
    k_scan3<<<(n1 + 255) / 256, 256, 0, stream>>>(blksum, row_ptr, counts, n1);
    k_scatter<<<(E + 255) / 256, 256, 0, stream>>>(erow, ecol, evals, counts, cols_s, vals_s, E);

    k_build_m<<<DD, DD, 0, stream>>>(W, dvec, Mpk);
    k_init<<<(N * 64 + 255) / 256, 256, 0, stream>>>(x, alpha0, znb, xb, alpha, N);

    const float dt = 0.45f;  // T_END / N_STEPS
    int gs = (N + 3) / 4, ge = (N + 31) / 32;
    for (int s = 0; s < 2; s++) {
        // eval1: z = znb -> z1 (B1)
        k_spmm<<<gs, 256, 0, stream>>>(znb, row_ptr, cols_s, vals_s, W_ih, W_hh,
                                       b_ih, b_hh, h, alpha, alph, az, N);
        k_eval<<<ge, 256, 0, stream>>>(znb, znb, B1, nullptr, nullptr, nullptr,
                                       az, Mpk, xb, alph, N, 0, 0.5f * dt, 0.f);
        // eval2: z = z1 (B1) -> z2 (B1 in-place), D -> P
        k_spmm<<<gs, 256, 0, stream>>>(B1, row_ptr, cols_s, vals_s, W_ih, W_hh,
                                       b_ih, b_hh, h, alpha, alph, az, N);
        k_eval<<<ge, 256, 0, stream>>>(B1, znb, B1, P, nullptr, nullptr,
                                       az, Mpk, xb, alph, N, 1, 0.5f * dt, 0.f);
        // eval3: z = z2 (B1) -> z3 (B1 in-place)
        k_spmm<<<gs, 256, 0, stream>>>(B1, row_ptr, cols_s, vals_s, W_ih, W_hh,
                                       b_ih, b_hh, h, alpha, alph, az, N);
        k_eval<<<ge, 256, 0, stream>>>(B1, znb, B1, nullptr, nullptr, nullptr,
                                       az, Mpk, xb, alph, N, 2, dt, 0.f);
        // eval4: z = z3 (B1) -> znew (znb in-place / f32 out)
        k_spmm<<<gs, 256, 0, stream>>>(B1, row_ptr, cols_s, vals_s, W_ih, W_hh,
                                       b_ih, b_hh, h, alpha, alph, az, N);
        if (s == 0) {
            k_eval<<<ge, 256, 0, stream>>>(B1, znb, znb, nullptr, P, nullptr,
                                           az, Mpk, xb, alph, N, 3, 0.f, dt / 6.f);
        } else {
            // final: emit fp32 output directly (first 128 cols)
            k_eval<<<ge, 256, 0, stream>>>(B1, znb, nullptr, nullptr, P,
                                           (float*)d_out, az, Mpk, xb, alph,
                                           N, 4, 0.f, dt / 6.f);
        }
    }
}

// Round 8
// 1421.447 us; speedup vs baseline: 1.5275x; 1.0144x over previous
//
#include <hip/hip_runtime.h>
#include <stdint.h>

#define DD 256
#define DINF 128

typedef __attribute__((ext_vector_type(8))) short short8;
typedef __attribute__((ext_vector_type(4))) float f32x4;

__device__ __forceinline__ short f2bf(float f) {
    union { float f; uint32_t u; } c{f};
    uint32_t r = (c.u + 0x7fffu + ((c.u >> 16) & 1u)) >> 16;
    return (short)(uint16_t)r;
}

__device__ __forceinline__ float bf2f(uint16_t b) {
    union { uint32_t u; float f; } c;
    c.u = ((uint32_t)b) << 16;
    return c.f;
}

// ---------------- CSR build ----------------
__global__ void k_hist(const int* __restrict__ rows, int* __restrict__ counts, int E) {
    int e = blockIdx.x * blockDim.x + threadIdx.x;
    if (e < E) atomicAdd(&counts[rows[e] + 1], 1);
}

__global__ void k_scan1(const int* __restrict__ counts, int* __restrict__ part,
                        int* __restrict__ blksum, int n1) {
    __shared__ int tmp[1024];
    int b = blockIdx.x, t = threadIdx.x, i = b * 1024 + t;
    int v = (i < n1) ? counts[i] : 0;
    tmp[t] = v;
    __syncthreads();
    for (int off = 1; off < 1024; off <<= 1) {
        int a = (t >= off) ? tmp[t - off] : 0;
        __syncthreads();
        tmp[t] += a;
        __syncthreads();
    }
    if (i < n1) part[i] = tmp[t];
    if (t == 1023) blksum[b] = tmp[t];
}

__global__ void k_scan2(int* __restrict__ blksum, int nb) {
    __shared__ int tmp[1024];
    int t = threadIdx.x;
    int v = (t < nb) ? blksum[t] : 0;
    tmp[t] = v;
    __syncthreads();
    for (int off = 1; off < 1024; off <<= 1) {
        int a = (t >= off) ? tmp[t - off] : 0;
        __syncthreads();
        tmp[t] += a;
        __syncthreads();
    }
    if (t < nb) blksum[t] = tmp[t];
}

__global__ void k_scan3(const int* __restrict__ blksum, int* __restrict__ row_ptr,
                        int* __restrict__ cursor, int n1) {
    int i = blockIdx.x * blockDim.x + threadIdx.x;
    if (i < n1) {
        int b = i >> 10;
        int off = (b > 0) ? blksum[b - 1] : 0;
        int v = row_ptr[i] + off;
        row_ptr[i] = v;
        cursor[i] = v;
    }
}

__global__ void k_scatter(const int* __restrict__ rows, const int* __restrict__ cols,
                          const float* __restrict__ vals, int* __restrict__ cursor,
                          int* __restrict__ cols_s, float* __restrict__ vals_s, int E) {
    int e = blockIdx.x * blockDim.x + threadIdx.x;
    if (e < E) {
        int r = rows[e];
        int pos = atomicAdd(&cursor[r], 1);
        cols_s[pos] = cols[e];
        vals_s[pos] = vals[e];
    }
}

// ---------------- M = (W*clip(d))@W^T - I, packed in MFMA B-fragment order ----------------
__global__ void k_build_m(const float* __restrict__ W, const float* __restrict__ dvec,
                          uint16_t* __restrict__ Mpk) {
    __shared__ float u[DD];
    int n = blockIdx.x, k = threadIdx.x;
    float dj = dvec[k];
    dj = fminf(fmaxf(dj, 0.f), 1.f);
    u[k] = W[n * DD + k] * dj;
    __syncthreads();
    float acc = 0.f;
    for (int j = 0; j < DD; j++) acc += u[j] * W[k * DD + j];
    acc -= (n == k) ? 1.f : 0.f;
    int tile = n >> 4, m = n & 15, kt = k >> 5, quad = (k >> 3) & 3, j = k & 7;
    int lane = quad * 16 + m;
    Mpk[(((tile * 8 + kt) * 64 + lane) << 3) + j] = (uint16_t)f2bf(acc);
}

// ---------------- init: znb = bf16([x,0]), xb = bf16(x), alpha = alpha0 ----------------
__global__ void k_init(const float* __restrict__ x, const float* __restrict__ alpha0,
                       uint16_t* __restrict__ znb, uint16_t* __restrict__ xb,
                       float* __restrict__ alpha, int N) {
    int idx = blockIdx.x * blockDim.x + threadIdx.x;
    int total = N * 64;
    if (idx < total) {
        int row = idx >> 6, c4 = idx & 63;
        float4 v = make_float4(0.f, 0.f, 0.f, 0.f);
        if (c4 < 32) v = ((const float4*)x)[(size_t)row * 32 + c4];
        ushort4 b;
        b.x = (uint16_t)f2bf(v.x); b.y = (uint16_t)f2bf(v.y);
        b.z = (uint16_t)f2bf(v.z); b.w = (uint16_t)f2bf(v.w);
        ((ushort4*)znb)[idx] = b;
        if (c4 < 32) ((ushort4*)xb)[(size_t)row * 32 + c4] = b;
    }
    if (idx < N) alpha[idx] = alpha0[idx];
}

// ---------------- fused eval: gather(az in regs) + alpha + z@M (MFMA) + RK4 -------
// Block = 512 threads (8 waves), 16 rows. Wave w: gathers/combines rows 2w,2w+1;
// MFMA col-tiles 2w,2w+1 for all 16 rows. az never touches memory.
// f = alph*(az - z) + z@M + x0
// mode 0: zout = bf16(z + c1*f)
// mode 1: z2f = znb + c1*f; zout = bf16(z2f); Pout = bf16(z + 2*z2f - 3*znb)
// mode 2: zout = bf16(znb + c1*f)
// mode 3: znew = znb + (P + z - znb)/3 + c2*f; zout = bf16(znew)
// mode 4: same as 3 but f32 out (first 128 cols), no zout
// Aliasing: zout never aliases zsrc (gather reads zsrc cross-block). znb may be
// written in mode 3 (zout==znb): znb is only accessed at own rows there.
__global__ __launch_bounds__(512, 6) void k_fused(
    const uint16_t* zsrc, const uint16_t* znb, uint16_t* zout,
    uint16_t* __restrict__ Pout, const uint16_t* __restrict__ Pin,
    float* __restrict__ out,
    const uint16_t* __restrict__ Mpk, const uint16_t* __restrict__ xb,
    const int* __restrict__ row_ptr, const int* __restrict__ cols_s,
    const float* __restrict__ vals_s,
    const float* __restrict__ W_ih, const float* __restrict__ W_hh,
    const float* __restrict__ b_ih, const float* __restrict__ b_hh,
    const float* __restrict__ hbuf, float* __restrict__ alpha,
    int N, int mode, float c1, float c2)
{
    __shared__ uint16_t gs[16][264];   // z@M result, bf16  ~8.4 KB

    int t = threadIdx.x;
    int wv = t >> 6;            // 0..7
    int lane = t & 63;
    int r0 = blockIdx.x * 16;

    int row0 = wv * 2, row1 = wv * 2 + 1;
    int g0 = r0 + row0, g1 = r0 + row1;
    bool ok0 = g0 < N, ok1 = g1 < N;

    // own-row eval points (cols 4*lane..+3)
    ushort4 zr0 = ok0 ? ((const ushort4*)zsrc)[(size_t)g0 * 64 + lane] : make_ushort4(0,0,0,0);
    ushort4 zr1 = ok1 ? ((const ushort4*)zsrc)[(size_t)g1 * 64 + lane] : make_ushort4(0,0,0,0);

    // ---- gather both rows (az in f32 regs), interleaved chunk-4 ----
    int s0e = ok0 ? row_ptr[g0] : 0, e0e = ok0 ? row_ptr[g0 + 1] : 0;
    int s1e = ok1 ? row_ptr[g1] : 0, e1e = ok1 ? row_ptr[g1 + 1] : 0;
    int d0 = e0e - s0e, d1 = e1e - s1e;
    int dmax = (d0 > d1) ? d0 : d1;
    float4 az0 = make_float4(0.f, 0.f, 0.f, 0.f);
    float4 az1 = make_float4(0.f, 0.f, 0.f, 0.f);
    for (int i = 0; i < dmax; i += 4) {
        if (i < d0) {
            int rem = d0 - i, base = s0e + i;
            int ca = cols_s[base];
            float va = vals_s[base];
            int cb = 0, cc = 0, cd = 0;
            float vb = 0.f, vc = 0.f, vd = 0.f;
            if (rem > 1) { cb = cols_s[base + 1]; vb = vals_s[base + 1]; }
            if (rem > 2) { cc = cols_s[base + 2]; vc = vals_s[base + 2]; }
            if (rem > 3) { cd = cols_s[base + 3]; vd = vals_s[base + 3]; }
            ushort4 ra = ((const ushort4*)zsrc)[(size_t)ca * 64 + lane];
            ushort4 rb = (rem > 1) ? ((const ushort4*)zsrc)[(size_t)cb * 64 + lane] : make_ushort4(0,0,0,0);
            ushort4 rc = (rem > 2) ? ((const ushort4*)zsrc)[(size_t)cc * 64 + lane] : make_ushort4(0,0,0,0);
            ushort4 rd = (rem > 3) ? ((const ushort4*)zsrc)[(size_t)cd * 64 + lane] : make_ushort4(0,0,0,0);
            az0.x += va * bf2f(ra.x) + vb * bf2f(rb.x) + vc * bf2f(rc.x) + vd * bf2f(rd.x);
            az0.y += va * bf2f(ra.y) + vb * bf2f(rb.y) + vc * bf2f(rc.y) + vd * bf2f(rd.y);
            az0.z += va * bf2f(ra.z) + vb * bf2f(rb.z) + vc * bf2f(rc.z) + vd * bf2f(rd.z);
            az0.w += va * bf2f(ra.w) + vb * bf2f(rb.w) + vc * bf2f(rc.w) + vd * bf2f(rd.w);
        }
        if (i < d1) {
            int rem = d1 - i, base = s1e + i;
            int ca = cols_s[base];
            float va = vals_s[base];
            int cb = 0, cc = 0, cd = 0;
            float vb = 0.f, vc = 0.f, vd = 0.f;
            if (rem > 1) { cb = cols_s[base + 1]; vb = vals_s[base + 1]; }
            if (rem > 2) { cc = cols_s[base + 2]; vc = vals_s[base + 2]; }
            if (rem > 3) { cd = cols_s[base + 3]; vd = vals_s[base + 3]; }
            ushort4 ra = ((const ushort4*)zsrc)[(size_t)ca * 64 + lane];
            ushort4 rb = (rem > 1) ? ((const ushort4*)zsrc)[(size_t)cb * 64 + lane] : make_ushort4(0,0,0,0);
            ushort4 rc = (rem > 2) ? ((const ushort4*)zsrc)[(size_t)cc * 64 + lane] : make_ushort4(0,0,0,0);
            ushort4 rd = (rem > 3) ? ((const ushort4*)zsrc)[(size_t)cd * 64 + lane] : make_ushort4(0,0,0,0);
            az1.x += va * bf2f(ra.x) + vb * bf2f(rb.x) + vc * bf2f(rc.x) + vd * bf2f(rd.x);
            az1.y += va * bf2f(ra.y) + vb * bf2f(rb.y) + vc * bf2f(rc.y) + vd * bf2f(rd.y);
            az1.z += va * bf2f(ra.z) + vb * bf2f(rb.z) + vc * bf2f(rc.z) + vd * bf2f(rd.z);
            az1.w += va * bf2f(ra.w) + vb * bf2f(rb.w) + vc * bf2f(rc.w) + vd * bf2f(rd.w);
        }
    }

    // ---- MFMA: col tiles 2w, 2w+1 over all 16 block rows ----
    int m = lane & 15, quad = lane >> 4;
    int t0 = wv * 2, t1 = wv * 2 + 1;
    int arow_g = r0 + m;
    bool aok = arow_g < N;
    f32x4 acc0 = {0.f, 0.f, 0.f, 0.f};
    f32x4 acc1 = {0.f, 0.f, 0.f, 0.f};
    #pragma unroll
    for (int kt = 0; kt < 8; kt++) {
        short8 a = aok ? *(const short8*)(zsrc + (size_t)arow_g * 256 + kt * 32 + quad * 8)
                       : short8{0, 0, 0, 0, 0, 0, 0, 0};
        short8 b0 = ((const short8*)Mpk)[(t0 * 8 + kt) * 64 + lane];
        short8 b1 = ((const short8*)Mpk)[(t1 * 8 + kt) * 64 + lane];
        acc0 = __builtin_amdgcn_mfma_f32_16x16x32_bf16(a, b0, acc0, 0, 0, 0);
        acc1 = __builtin_amdgcn_mfma_f32_16x16x32_bf16(a, b1, acc1, 0, 0, 0);
    }
    // C layout: col = lane&15, row = quad*4 + r
    #pragma unroll
    for (int r = 0; r < 4; r++) {
        gs[quad * 4 + r][t0 * 16 + m] = (uint16_t)f2bf(acc0[r]);
        gs[quad * 4 + r][t1 * 16 + m] = (uint16_t)f2bf(acc1[r]);
    }

    // ---- alpha RNN update for both rows (while MFMA stores settle) ----
    float4 wih0 = ((const float4*)W_ih)[lane];
    float4 wih1 = ((const float4*)(W_ih + DD))[lane];
    float z00 = bf2f(zr0.x), z01 = bf2f(zr0.y), z02 = bf2f(zr0.z), z03 = bf2f(zr0.w);
    float z10 = bf2f(zr1.x), z11 = bf2f(zr1.y), z12 = bf2f(zr1.z), z13 = bf2f(zr1.w);
    float s00 = z00 * wih0.x + z01 * wih0.y + z02 * wih0.z + z03 * wih0.w;
    float s01 = z00 * wih1.x + z01 * wih1.y + z02 * wih1.z + z03 * wih1.w;
    float s10 = z10 * wih0.x + z11 * wih0.y + z12 * wih0.z + z13 * wih0.w;
    float s11 = z10 * wih1.x + z11 * wih1.y + z12 * wih1.z + z13 * wih1.w;
    #pragma unroll
    for (int off = 32; off >= 1; off >>= 1) {
        s00 += __shfl_down(s00, off, 64);
        s01 += __shfl_down(s01, off, 64);
        s10 += __shfl_down(s10, off, 64);
        s11 += __shfl_down(s11, off, 64);
    }
    float alph0 = 0.f, alph1 = 0.f;
    if (lane == 0) {
        float bi0 = b_ih[0] + b_hh[0], bi1 = b_ih[1] + b_hh[1];
        float wh0 = W_hh[0], wh1 = W_hh[1], wh2 = W_hh[2], wh3 = W_hh[3];
        if (ok0) {
            float h0 = hbuf[g0 * 2], h1 = hbuf[g0 * 2 + 1];
            float anew = alpha[g0] * tanhf(s00 + bi0 + h0 * wh0 + h1 * wh1)
                       + tanhf(s01 + bi1 + h0 * wh2 + h1 * wh3);
            alpha[g0] = anew;
            alph0 = 0.5f / (1.f + expf(-anew));
        }
        if (ok1) {
            float h0 = hbuf[g1 * 2], h1 = hbuf[g1 * 2 + 1];
            float anew = alpha[g1] * tanhf(s10 + bi0 + h0 * wh0 + h1 * wh1)
                       + tanhf(s11 + bi1 + h0 * wh2 + h1 * wh3);
            alpha[g1] = anew;
            alph1 = 0.5f / (1.f + expf(-anew));
        }
    }
    alph0 = __shfl(alph0, 0, 64);
    alph1 = __shfl(alph1, 0, 64);

    __syncthreads();

    // ---- combine + RK4 for this wave's two rows ----
    #pragma unroll
    for (int rr = 0; rr < 2; rr++) {
        int rowloc = (rr == 0) ? row0 : row1;
        int grow = (rr == 0) ? g0 : g1;
        bool ok = (rr == 0) ? ok0 : ok1;
        if (!ok) continue;
        float4 azv = (rr == 0) ? az0 : az1;
        ushort4 z4 = (rr == 0) ? zr0 : zr1;
        float al = (rr == 0) ? alph0 : alph1;
        size_t b4 = (size_t)grow * 64 + lane;
        ushort4 g4 = *(const ushort4*)&gs[rowloc][lane * 4];
        float4 x4 = make_float4(0.f, 0.f, 0.f, 0.f);
        if (lane < 32) {
            ushort4 xb4 = ((const ushort4*)xb)[(size_t)grow * 32 + lane];
            x4.x = bf2f(xb4.x); x4.y = bf2f(xb4.y);
            x4.z = bf2f(xb4.z); x4.w = bf2f(xb4.w);
        }
        float zv0 = bf2f(z4.x), zv1 = bf2f(z4.y), zv2 = bf2f(z4.z), zv3 = bf2f(z4.w);
        float f0 = al * (azv.x - zv0) + bf2f(g4.x) + x4.x;
        float f1 = al * (azv.y - zv1) + bf2f(g4.y) + x4.y;
        float f2 = al * (azv.z - zv2) + bf2f(g4.z) + x4.z;
        float f3 = al * (azv.w - zv3) + bf2f(g4.w) + x4.w;
        if (mode == 0) {
            ushort4 o;
            o.x = (uint16_t)f2bf(zv0 + c1 * f0); o.y = (uint16_t)f2bf(zv1 + c1 * f1);
            o.z = (uint16_t)f2bf(zv2 + c1 * f2); o.w = (uint16_t)f2bf(zv3 + c1 * f3);
            ((ushort4*)zout)[b4] = o;
        } else if (mode == 1) {
            ushort4 zb = ((const ushort4*)znb)[b4];
            float zb0 = bf2f(zb.x), zb1 = bf2f(zb.y), zb2 = bf2f(zb.z), zb3 = bf2f(zb.w);
            float z20 = zb0 + c1 * f0, z21 = zb1 + c1 * f1;
            float z22 = zb2 + c1 * f2, z23 = zb3 + c1 * f3;
            ushort4 o, p;
            o.x = (uint16_t)f2bf(z20); o.y = (uint16_t)f2bf(z21);
            o.z = (uint16_t)f2bf(z22); o.w = (uint16_t)f2bf(z23);
            p.x = (uint16_t)f2bf(zv0 + 2.f * z20 - 3.f * zb0);
            p.y = (uint16_t)f2bf(zv1 + 2.f * z21 - 3.f * zb1);
            p.z = (uint16_t)f2bf(zv2 + 2.f * z22 - 3.f * zb2);
            p.w = (uint16_t)f2bf(zv3 + 2.f * z23 - 3.f * zb3);
            ((ushort4*)zout)[b4] = o;
            ((ushort4*)Pout)[b4] = p;
        } else if (mode == 2) {
            ushort4 zb = ((const ushort4*)znb)[b4];
            ushort4 o;
            o.x = (uint16_t)f2bf(bf2f(zb.x) + c1 * f0);
            o.y = (uint16_t)f2bf(bf2f(zb.y) + c1 * f1);
            o.z = (uint16_t)f2bf(bf2f(zb.z) + c1 * f2);
            o.w = (uint16_t)f2bf(bf2f(zb.w) + c1 * f3);
            ((ushort4*)zout)[b4] = o;
        } else {
            // znew = znb + (P + z3 - znb)/3 + c2*f
            ushort4 zb4 = ((const ushort4*)znb)[b4];
            ushort4 p4 = ((const ushort4*)Pin)[b4];
            const float third = 1.f / 3.f;
            float zb0 = bf2f(zb4.x), zb1 = bf2f(zb4.y), zb2 = bf2f(zb4.z), zb3 = bf2f(zb4.w);
            float r0v = zb0 + (bf2f(p4.x) + zv0 - zb0) * third + c2 * f0;
            float r1v = zb1 + (bf2f(p4.y) + zv1 - zb1) * third + c2 * f1;
            float r2v = zb2 + (bf2f(p4.z) + zv2 - zb2) * third + c2 * f2;
            float r3v = zb3 + (bf2f(p4.w) + zv3 - zb3) * third + c2 * f3;
            if (mode == 3) {
                ushort4 o;
                o.x = (uint16_t)f2bf(r0v); o.y = (uint16_t)f2bf(r1v);
                o.z = (uint16_t)f2bf(r2v); o.w = (uint16_t)f2bf(r3v);
                ((ushort4*)zout)[b4] = o;
            } else {
                if (lane < 32) {
                    float4 o;
                    o.x = r0v; o.y = r1v; o.z = r2v; o.w = r3v;
                    ((float4*)out)[(size_t)grow * 32 + lane] = o;
                }
            }
        }
    }
}

__global__ void k_fill(float* __restrict__ out, int n, float v) {
    int idx = blockIdx.x * blockDim.x + threadIdx.x;
    if (idx < n) out[idx] = v;
}

static inline size_t alignup(size_t v) { return (v + 255) & ~(size_t)255; }

extern "C" void kernel_launch(void* const* d_in, const int* in_sizes, int n_in,
                              void* d_out, int out_size, void* d_ws, size_t ws_size,
                              hipStream_t stream) {
    const float* x      = (const float*)d_in[0];
    const int*   erow   = (const int*)d_in[1];
    const int*   ecol   = (const int*)d_in[2];
    const float* evals  = (const float*)d_in[3];
    const float* W_ih   = (const float*)d_in[4];
    const float* W_hh   = (const float*)d_in[5];
    const float* b_ih   = (const float*)d_in[6];
    const float* b_hh   = (const float*)d_in[7];
    const float* h      = (const float*)d_in[8];
    const float* alpha0 = (const float*)d_in[9];
    const float* W      = (const float*)d_in[10];
    const float* dvec   = (const float*)d_in[11];

    int N = in_sizes[0] / DINF;
    int E = in_sizes[1];

    char* w = (char*)d_ws;
    uint16_t* znb = (uint16_t*)w; w += alignup((size_t)N * DD * 2);   //  51.2 MB
    uint16_t* B1  = (uint16_t*)w; w += alignup((size_t)N * DD * 2);   //  51.2 MB (z1 / z3)
    uint16_t* P   = (uint16_t*)w; w += alignup((size_t)N * DD * 2);   //  51.2 MB (D-fold)
    uint16_t* xb  = (uint16_t*)w; w += alignup((size_t)N * DINF * 2); //  25.6 MB
    float* alpha = (float*)w;     w += alignup((size_t)N * 4);
    uint16_t* Mpk = (uint16_t*)w; w += alignup((size_t)DD * DD * 2);
    int* counts = (int*)w;        w += alignup((size_t)(N + 1) * 4);  // reused as cursor
    int* row_ptr = (int*)w;       w += alignup((size_t)(N + 1) * 4);
    int* blksum = (int*)w;        w += alignup((size_t)1024 * 4);
    int* cols_s = (int*)w;        w += alignup((size_t)E * 4);
    float* vals_s = (float*)w;    w += alignup((size_t)E * 4);
    size_t need = (size_t)(w - (char*)d_ws);   // ~187 MB

    // B2 (z2) lives in d_out (N*128 f32 = N*256 bf16 exactly); dead after eval3's
    // gather; final mode-4 eval overwrites d_out with the fp32 result.
    uint16_t* B2 = (uint16_t*)d_out;

    if (ws_size < need) {
        k_fill<<<(out_size + 255) / 256, 256, 0, stream>>>((float*)d_out, out_size, 1000.0f);
        return;
    }

    int n1 = N + 1, nb = (n1 + 1023) / 1024;
    hipMemsetAsync(counts, 0, (size_t)n1 * 4, stream);
    k_hist<<<(E + 255) / 256, 256, 0, stream>>>(erow, counts, E);
    k_scan1<<<nb, 1024, 0, stream>>>(counts, row_ptr, blksum, n1);
    k_scan2<<<1, 1024, 0, stream>>>(blksum, nb);
    k_scan3<<<(n1 + 255) / 256, 256, 0, stream>>>(blksum, row_ptr, counts, n1);
    k_scatter<<<(E + 255) / 256, 256, 0, stream>>>(erow, ecol, evals, counts, cols_s, vals_s, E);

    k_build_m<<<DD, DD, 0, stream>>>(W, dvec, Mpk);
    k_init<<<(N * 64 + 255) / 256, 256, 0, stream>>>(x, alpha0, znb, xb, alpha, N);

    const float dt = 0.45f;  // T_END / N_STEPS
    int ge = (N + 15) / 16;
    for (int s = 0; s < 2; s++) {
        // eval1: znb -> z1 (B1)
        k_fused<<<ge, 512, 0, stream>>>(znb, znb, B1, nullptr, nullptr, nullptr,
                                        Mpk, xb, row_ptr, cols_s, vals_s,
                                        W_ih, W_hh, b_ih, b_hh, h, alpha,
                                        N, 0, 0.5f * dt, 0.f);
        // eval2: z1 (B1) -> z2 (B2=d_out), D -> P
        k_fused<<<ge, 512, 0, stream>>>(B1, znb, B2, P, nullptr, nullptr,
                                        Mpk, xb, row_ptr, cols_s, vals_s,
                                        W_ih, W_hh, b_ih, b_hh, h, alpha,
                                        N, 1, 0.5f * dt, 0.f);
        // eval3: z2 (B2) -> z3 (B1)
        k_fused<<<ge, 512, 0, stream>>>(B2, znb, B1, nullptr, nullptr, nullptr,
                                        Mpk, xb, row_ptr, cols_s, vals_s,
                                        W_ih, W_hh, b_ih, b_hh, h, alpha,
                                        N, 2, dt, 0.f);
        // eval4: z3 (B1) -> znew
        if (s == 0) {
            k_fused<<<ge, 512, 0, stream>>>(B1, znb, znb, nullptr, P, nullptr,
                                            Mpk, xb, row_ptr, cols_s, vals_s,
                                            W_ih, W_hh, b_ih, b_hh, h, alpha,
                                            N, 3, 0.f, dt / 6.f);
        } else {
            // final: emit fp32 output directly (first 128 cols)
            k_fused<<<ge, 512, 0, stream>>>(B1, znb, nullptr, nullptr, P,
                                            (float*)d_out,
                                            Mpk, xb, row_ptr, cols_s, vals_s,
                                            W_ih, W_hh, b_ih, b_hh, h, alpha,
                                            N, 4, 0.f, dt / 6.f);
        }
    }
}